// Round 16
// baseline (481.011 us; speedup 1.0000x reference)
//
#include <hip/hip_runtime.h>
#include <hip/hip_bf16.h>
#include <math.h>

#define B_ 256
#define T_ 256
#define CIN 64
#define HID 512
#define NH 8
#define HD 64
#define FFD 2048
#define OUTD 10

typedef __bf16 bf16x8 __attribute__((ext_vector_type(8)));
typedef float f32x4 __attribute__((ext_vector_type(4)));

// swizzled LDS byte offset for a [rows x 512] bf16 tile (row stride 1024B)
#define HSOFF(r,c) (((r)<<10) + ((((c)<<1)) ^ ((((r)&7))<<4)))
// swizzled LDS byte offset for a [rows x 2048] bf16 tile (row stride 4096B)
#define HS2OFF(r,c) (((r)<<12) + ((((c)<<1)) ^ ((((r)&7))<<4)))

__device__ __forceinline__ float bf2f(unsigned u){
  union { unsigned i; float f; } c; c.i = u << 16; return c.f;
}
__device__ __forceinline__ unsigned pk2(float a, float b){
  return ((unsigned)__bfloat16_as_ushort(__float2bfloat16(a))) |
         (((unsigned)__bfloat16_as_ushort(__float2bfloat16(b))) << 16);
}

// ---------------- pack: f32 weight (N x K) -> bf16 MFMA-fragment order ----------------
__device__ __forceinline__ void pack_one(const float* __restrict__ W,
                                         __hip_bfloat16* __restrict__ P,
                                         const int K, int g){
  int row = g / (K/8), kg = g % (K/8);
  int k0 = kg*8;
  int n0 = row >> 6, j = (row >> 4) & 3, lr = row & 15;
  int s = k0 >> 5, lg = (k0 >> 3) & 3;
  int lane = lg*16 + lr;
  const float* src = W + (size_t)row*K + k0;
  float4 a = *(const float4*)src;
  float4 b = *(const float4*)(src+4);
  uint4 p = { pk2(a.x,a.y), pk2(a.z,a.w), pk2(b.x,b.y), pk2(b.z,b.w) };
  size_t off = ((((size_t)n0*(K>>5) + s)*4 + j)*64 + lane)*8;
  *(uint4*)(P + off) = p;
}

#define G_KV (HID*HID/8)   // 32768
#define G_FF (FFD*HID/8)   // 131072
#define G_IP (HID*CIN/8)   // 4096
#define G_I  (CIN*128/8)   // 1024
#define PK_TOT (4*G_KV + 2*G_FF + G_IP + G_I)
__global__ __launch_bounds__(256) void k_pack(
    const float* __restrict__ Wk, const float* __restrict__ Wv,
    const float* __restrict__ Wo, const float* __restrict__ Wq,
    const float* __restrict__ W1, const float* __restrict__ W2,
    const float* __restrict__ Wip, const float* __restrict__ Wi,
    __hip_bfloat16* __restrict__ Pk, __hip_bfloat16* __restrict__ Pv,
    __hip_bfloat16* __restrict__ Po, __hip_bfloat16* __restrict__ Pq,
    __hip_bfloat16* __restrict__ P1, __hip_bfloat16* __restrict__ P2,
    __hip_bfloat16* __restrict__ Pip, __hip_bfloat16* __restrict__ Pi)
{
  int g = blockIdx.x*256 + threadIdx.x;
  if (g < G_KV) { pack_one(Wk, Pk, HID, g); return; }  g -= G_KV;
  if (g < G_KV) { pack_one(Wv, Pv, HID, g); return; }  g -= G_KV;
  if (g < G_KV) { pack_one(Wo, Po, HID, g); return; }  g -= G_KV;
  if (g < G_KV) { pack_one(Wq, Pq, HID, g); return; }  g -= G_KV;
  if (g < G_FF) { pack_one(W1, P1, HID, g); return; }  g -= G_FF;
  if (g < G_FF) { pack_one(W2, P2, FFD, g); return; }  g -= G_FF;
  if (g < G_IP) { pack_one(Wip, Pip, CIN, g); return; }  g -= G_IP;
  if (g < G_I ) { pack_one(Wi, Pi, 128, g); }
}

// ---- building block (M=16): A(16x64 in Hs cols 0..64) @ Wip^T + LN -> Hs (16x512 bf16) ----
__device__ __forceinline__ void proj_ln16(
    char* Hs, const __hip_bfloat16* __restrict__ Pip,
    const float* __restrict__ bip, const float* __restrict__ g_in,
    const float* __restrict__ b_in,
    float (*red)[8][2], float (*ms2)[2],
    int tid, int w, int l, int lr, int lg)
{
  f32x4 acc[4];
  #pragma unroll
  for (int j=0;j<4;j++) acc[j] = (f32x4){0.f,0.f,0.f,0.f};
  #pragma unroll
  for (int s = 0; s < 2; s++){
    bf16x8 af = *(const bf16x8*)(Hs + HSOFF(lr, s*32 + lg*8));
    const __hip_bfloat16* fb = Pip + ((size_t)(w*2 + s)*4)*512 + l*8;
    #pragma unroll
    for (int j=0;j<4;j++){
      bf16x8 bfr = *(const bf16x8*)(fb + j*512);
      acc[j] = __builtin_amdgcn_mfma_f32_16x16x32_bf16(af, bfr, acc[j], 0,0,0);
    }
  }
  float bipv[4], gv[4], bbv[4];
  #pragma unroll
  for (int j=0;j<4;j++){
    int col = w*64 + j*16 + lr;
    bipv[j] = bip[col]; gv[j] = g_in[col]; bbv[j] = b_in[col];
  }
  #pragma unroll
  for (int r=0;r<4;r++){
    float s = 0.f, s2 = 0.f;
    #pragma unroll
    for (int j=0;j<4;j++){ float v = acc[j][r] + bipv[j]; s += v; s2 += v*v; }
    #pragma unroll
    for (int o=1;o<16;o<<=1){ s += __shfl_xor(s,o); s2 += __shfl_xor(s2,o); }
    if (lr == 0){ int row = lg*4 + r; red[row][w][0] = s; red[row][w][1] = s2; }
  }
  __syncthreads();
  if (tid < 16){
    float S = 0.f, S2 = 0.f;
    #pragma unroll
    for (int k=0;k<8;k++){ S += red[tid][k][0]; S2 += red[tid][k][1]; }
    float m = S*(1.f/512.f), var = S2*(1.f/512.f) - m*m;
    ms2[tid][0] = m; ms2[tid][1] = rsqrtf(var + 1e-5f);
  }
  __syncthreads();
  #pragma unroll
  for (int r=0;r<4;r++){
    int row = lg*4 + r;
    float m = ms2[row][0], rs = ms2[row][1];
    #pragma unroll
    for (int j=0;j<4;j++){
      int col = w*64 + j*16 + lr;
      float v = (acc[j][r] + bipv[j] - m)*rs*gv[j] + bbv[j];
      *(unsigned short*)(Hs + HSOFF(row, col)) =
          __bfloat16_as_ushort(__float2bfloat16(v));
    }
  }
  __syncthreads();
}

// ---- building block (M=16): acc = Hs(16x512) @ P^T (K=512, packed, n0 pre-applied) ----
__device__ __forceinline__ void gemm512_pk16(
    const char* Hs, const __hip_bfloat16* __restrict__ Pm,
    f32x4 acc[4], int l, int lr, int lg)
{
  #pragma unroll
  for (int j=0;j<4;j++) acc[j] = (f32x4){0.f,0.f,0.f,0.f};
  #pragma unroll
  for (int s = 0; s < 16; s++){
    bf16x8 af = *(const bf16x8*)(Hs + HSOFF(lr, s*32 + lg*8));
    const __hip_bfloat16* fb = Pm + (size_t)s*2048 + l*8;
    #pragma unroll
    for (int j=0;j<4;j++){
      bf16x8 bfr = *(const bf16x8*)(fb + j*512);
      acc[j] = __builtin_amdgcn_mfma_f32_16x16x32_bf16(af, bfr, acc[j], 0,0,0);
    }
  }
}

// ---------------- k_pre: batched init path (q, yinit), 16 blocks x 16 batch rows ----------
__global__ __launch_bounds__(512) void k_pre(
    const float* __restrict__ initial, const float* __restrict__ logsig,
    const __hip_bfloat16* __restrict__ Pi,  const float* __restrict__ bi,
    const __hip_bfloat16* __restrict__ Pip, const float* __restrict__ bip,
    const float* __restrict__ g_in, const float* __restrict__ b_in,
    const __hip_bfloat16* __restrict__ Pq, const float* __restrict__ bq,
    const __hip_bfloat16* __restrict__ Pk, const float* __restrict__ bk,
    const __hip_bfloat16* __restrict__ Pv, const float* __restrict__ bv,
    float* __restrict__ qout, float* __restrict__ yinit)
{
  int b0 = blockIdx.x*16;
  int tid = threadIdx.x;
  int w = tid >> 6, l = tid & 63, lr = l & 15, lg = l >> 4;
  __shared__ __align__(16) char Hs[16*1024];
  __shared__ float red[16][8][2];
  __shared__ float ms2[16][2];
  __shared__ float salS[16][8];
  f32x4 acc[4];

  // ---- phase A: stage xlast (16 rows x 64 cols) -> Hs; hq = LN(x @ Wip^T) ----
  {
    int row = tid >> 5, c = (tid & 31)*2;
    const float* s = logsig + ((size_t)(b0+row)*T_ + (T_-1))*CIN + c;
    float2 a = *(const float2*)s;
    *(unsigned*)(Hs + HSOFF(row, c)) = pk2(a.x, a.y);
  }
  __syncthreads();
  proj_ln16(Hs, Pip, bip, g_in, b_in, red, ms2, tid, w, l, lr, lg);

  // ---- phase B: q = softmax_h(hq @ Wq_h^T + bq), kept in registers ----
  float qreg[4][4];   // [j][r]
  gemm512_pk16(Hs, Pq + (size_t)w*32768, acc, l, lr, lg);
  {
    float bqv[4];
    #pragma unroll
    for (int j=0;j<4;j++) bqv[j] = bq[w*64 + j*16 + lr];
    #pragma unroll
    for (int r=0;r<4;r++){
      float v0 = acc[0][r]+bqv[0], v1 = acc[1][r]+bqv[1];
      float v2 = acc[2][r]+bqv[2], v3 = acc[3][r]+bqv[3];
      float mx = fmaxf(fmaxf(v0,v1),fmaxf(v2,v3));
      #pragma unroll
      for (int o=1;o<16;o<<=1) mx = fmaxf(mx, __shfl_xor(mx,o));
      float e0=__expf(v0-mx), e1=__expf(v1-mx), e2=__expf(v2-mx), e3=__expf(v3-mx);
      float se = e0+e1+e2+e3;
      #pragma unroll
      for (int o=1;o<16;o<<=1) se += __shfl_xor(se,o);
      float inv = 1.f/se;
      qreg[0][r]=e0*inv; qreg[1][r]=e1*inv; qreg[2][r]=e2*inv; qreg[3][r]=e3*inv;
      int row = lg*4 + r;
      size_t base = (size_t)(b0+row)*HID + w*64 + lr;
      qout[base +  0] = qreg[0][r]; qout[base + 16] = qreg[1][r];
      qout[base + 32] = qreg[2][r]; qout[base + 48] = qreg[3][r];
    }
  }
  __syncthreads();

  // ---- phase C: stage initial (16x128) -> Hs cols 64..192; ip = initial@Wi^T+bi -> cols 0..64
  {
    int row = tid >> 5, c = (tid & 31)*4;
    const float* s = initial + (size_t)(b0+row)*128 + c;
    float4 a = *(const float4*)s;
    uint2 p = { pk2(a.x,a.y), pk2(a.z,a.w) };
    *(uint2*)(Hs + HSOFF(row, 64 + c)) = p;
  }
  __syncthreads();
  if (w < 4){
    f32x4 a2 = (f32x4){0.f,0.f,0.f,0.f};
    #pragma unroll
    for (int s = 0; s < 4; s++){
      bf16x8 af = *(const bf16x8*)(Hs + HSOFF(lr, 64 + s*32 + lg*8));
      bf16x8 bfr = *(const bf16x8*)(Pi + ((size_t)s*4 + w)*512 + l*8);
      a2 = __builtin_amdgcn_mfma_f32_16x16x32_bf16(af, bfr, a2, 0,0,0);
    }
    float bic = bi[w*16 + lr];
    #pragma unroll
    for (int r=0;r<4;r++){
      *(unsigned short*)(Hs + HSOFF(lg*4 + r, w*16 + lr)) =
          __bfloat16_as_ushort(__float2bfloat16(a2[r] + bic));
    }
  }
  __syncthreads();

  // ---- phase D: h0 = LN(ip @ Wip^T) -> Hs ----
  proj_ln16(Hs, Pip, bip, g_in, b_in, red, ms2, tid, w, l, lr, lg);

  // ---- phase E: k0 scores; sal = softmax(k0).q ----
  gemm512_pk16(Hs, Pk + (size_t)w*32768, acc, l, lr, lg);
  {
    float bkv[4];
    #pragma unroll
    for (int j=0;j<4;j++) bkv[j] = bk[w*64 + j*16 + lr];
    #pragma unroll
    for (int r=0;r<4;r++){
      float v0 = acc[0][r]+bkv[0], v1 = acc[1][r]+bkv[1];
      float v2 = acc[2][r]+bkv[2], v3 = acc[3][r]+bkv[3];
      float mx = fmaxf(fmaxf(v0,v1),fmaxf(v2,v3));
      #pragma unroll
      for (int o=1;o<16;o<<=1) mx = fmaxf(mx, __shfl_xor(mx,o));
      float e0=__expf(v0-mx), e1=__expf(v1-mx), e2=__expf(v2-mx), e3=__expf(v3-mx);
      float se = e0+e1+e2+e3;
      float sq = e0*qreg[0][r]+e1*qreg[1][r]+e2*qreg[2][r]+e3*qreg[3][r];
      #pragma unroll
      for (int o=1;o<16;o<<=1){ se += __shfl_xor(se,o); sq += __shfl_xor(sq,o); }
      if (lr == 0) salS[lg*4 + r][w] = sq/se;
    }
  }
  __syncthreads();

  // ---- phase F: v0; yinit = sal * v0 ----
  gemm512_pk16(Hs, Pv + (size_t)w*32768, acc, l, lr, lg);
  {
    float bvv[4];
    #pragma unroll
    for (int j=0;j<4;j++) bvv[j] = bv[w*64 + j*16 + lr];
    #pragma unroll
    for (int r=0;r<4;r++){
      int row = lg*4 + r;
      float s = salS[row][w];
      size_t base = (size_t)(b0+row)*HID + w*64 + lr;
      yinit[base +  0] = s*(acc[0][r]+bvv[0]);
      yinit[base + 16] = s*(acc[1][r]+bvv[1]);
      yinit[base + 32] = s*(acc[2][r]+bvv[2]);
      yinit[base + 48] = s*(acc[3][r]+bvv[3]);
    }
  }
}

// ---------------- FUSED kernel (operand-swapped, t-row-halved, SERIAL halves) --------------
// Thread (lr,lg) owns t-rows (ih*2+i2)*16+lr, cols (j*16+lg*4+r). acc2[4][2] = 32 VGPRs.
__global__ __launch_bounds__(512, 4) void k_fused(
    const float* __restrict__ logsig,
    const __hip_bfloat16* __restrict__ Pip,
    const float* __restrict__ bip,
    const float* __restrict__ g_in, const float* __restrict__ b_in,
    const __hip_bfloat16* __restrict__ Pk,
    const float* __restrict__ bk,
    const float* __restrict__ qws,             // (B,512)
    float* __restrict__ up,                    // (B,NH,4,512) f32 partial u
    float* __restrict__ Asp)                   // (B,NH,4) partial alpha-sum
{
  int b = blockIdx.x, tc = blockIdx.y;
  int tid = threadIdx.x;
  int w = tid >> 6, l = tid & 63, lr = l & 15, lg = l >> 4;
  __shared__ __align__(16) char Hs[64*1024];     // 64 rows x 512 bf16, swizzled
  __shared__ float red[64][8][2];
  __shared__ float ms2[64][2];
  __shared__ float als[64][8];
  __shared__ unsigned short als_bt[2][16][64];   // alpha^T bf16 hi/lo (rows 8-15 unused)

  // ---- stage logsig x-tile (64x64 f32 -> bf16) into Hs cols 0..64 ----
  {
    int row = tid >> 3, cc = (tid & 7)*8;
    const float* srow = logsig + ((size_t)b*T_ + tc*64 + row)*CIN + cc;
    float4 a = *(const float4*)(srow);
    float4 c = *(const float4*)(srow+4);
    uint4 p = { pk2(a.x,a.y), pk2(a.z,a.w), pk2(c.x,c.y), pk2(c.z,c.w) };
    *(uint4*)(Hs + HSOFF(row, cc)) = p;
  }
  __syncthreads();

  f32x4 acc2[4][2];   // [j][i2] : col j*16+lg*4+r, t-row (ih*2+i2)*16+lr

  // ---- phase 1 (swapped, halved, serial): Hpre = x @ Wip^T ; LN per t-row; write Hs ----
  #pragma unroll 1
  for (int ih = 0; ih < 2; ih++){
    #pragma unroll
    for (int j=0;j<4;j++)
      #pragma unroll
      for (int i=0;i<2;i++) acc2[j][i] = (f32x4){0.f,0.f,0.f,0.f};
    #pragma unroll
    for (int s = 0; s < 2; s++){
      bf16x8 wf[4], xf[2];
      const __hip_bfloat16* fb = Pip + ((size_t)(w*2 + s)*4)*512 + l*8;
      #pragma unroll
      for (int j=0;j<4;j++) wf[j] = *(const bf16x8*)(fb + j*512);
      #pragma unroll
      for (int i=0;i<2;i++)
        xf[i] = *(const bf16x8*)(Hs + HSOFF((ih*2+i)*16 + lr, s*32 + lg*8));
      #pragma unroll
      for (int j=0;j<4;j++)
        #pragma unroll
        for (int i=0;i<2;i++)
          acc2[j][i] = __builtin_amdgcn_mfma_f32_16x16x32_bf16(wf[j], xf[i], acc2[j][i], 0,0,0);
    }
    #pragma unroll
    for (int j=0;j<4;j++){
      float4 t = *(const float4*)(bip + w*64 + j*16 + lg*4);
      #pragma unroll
      for (int i=0;i<2;i++){
        acc2[j][i][0] += t.x; acc2[j][i][1] += t.y;
        acc2[j][i][2] += t.z; acc2[j][i][3] += t.w;
      }
    }
    #pragma unroll
    for (int i=0;i<2;i++){
      float s = 0.f, s2 = 0.f;
      #pragma unroll
      for (int j=0;j<4;j++){
        #pragma unroll
        for (int r=0;r<4;r++){ float v = acc2[j][i][r]; s += v; s2 += v*v; }
      }
      s += __shfl_xor(s,16); s2 += __shfl_xor(s2,16);
      s += __shfl_xor(s,32); s2 += __shfl_xor(s2,32);
      if (lg == 0){ int row = (ih*2+i)*16 + lr; red[row][w][0] = s; red[row][w][1] = s2; }
    }
    __syncthreads();
    if (tid < 32){
      int row = ih*32 + tid;
      float S = 0.f, S2 = 0.f;
      #pragma unroll
      for (int k=0;k<8;k++){ S += red[row][k][0]; S2 += red[row][k][1]; }
      float m = S*(1.f/512.f), var = S2*(1.f/512.f) - m*m;
      ms2[row][0] = m; ms2[row][1] = rsqrtf(var + 1e-5f);
    }
    __syncthreads();
    {
      float mA = ms2[ih*32 + lr][0],      rA = ms2[ih*32 + lr][1];
      float mB = ms2[ih*32 + 16 + lr][0], rB = ms2[ih*32 + 16 + lr][1];
      #pragma unroll
      for (int j=0;j<4;j++){
        int c0 = w*64 + j*16 + lg*4;
        float4 tg = *(const float4*)(g_in + c0);
        float4 tb = *(const float4*)(b_in + c0);
        #define LNWB(ii, MM, RR) { \
          float o0 = (acc2[j][ii][0]-MM)*RR*tg.x + tb.x; \
          float o1 = (acc2[j][ii][1]-MM)*RR*tg.y + tb.y; \
          float o2 = (acc2[j][ii][2]-MM)*RR*tg.z + tb.z; \
          float o3 = (acc2[j][ii][3]-MM)*RR*tg.w + tb.w; \
          uint2 pp = { pk2(o0,o1), pk2(o2,o3) }; \
          *(uint2*)(Hs + HSOFF((ih*2+ii)*16 + lr, c0)) = pp; }
        LNWB(0, mA, rA)
        LNWB(1, mB, rB)
        #undef LNWB
      }
    }
    __syncthreads();
  }

  // ---- phase 2+3 (swapped, halved, serial): S^T = Wk_h @ Hln^T; softmax + q-dot ----
  #pragma unroll 1
  for (int ih = 0; ih < 2; ih++){
    #pragma unroll
    for (int j=0;j<4;j++)
      #pragma unroll
      for (int i=0;i<2;i++) acc2[j][i] = (f32x4){0.f,0.f,0.f,0.f};
    const __hip_bfloat16* Pb = Pk + (size_t)w*32768 + l*8;
    #pragma unroll
    for (int s = 0; s < 16; s++){
      bf16x8 wf[4], xf[2];
      const __hip_bfloat16* fb = Pb + (size_t)s*2048;
      #pragma unroll
      for (int j=0;j<4;j++) wf[j] = *(const bf16x8*)(fb + j*512);
      #pragma unroll
      for (int i=0;i<2;i++)
        xf[i] = *(const bf16x8*)(Hs + HSOFF((ih*2+i)*16 + lr, s*32 + lg*8));
      #pragma unroll
      for (int j=0;j<4;j++)
        #pragma unroll
        for (int i=0;i<2;i++)
          acc2[j][i] = __builtin_amdgcn_mfma_f32_16x16x32_bf16(wf[j], xf[i], acc2[j][i], 0,0,0);
    }
    #pragma unroll
    for (int j=0;j<4;j++){
      float4 t = *(const float4*)(bk + w*64 + j*16 + lg*4);
      #pragma unroll
      for (int i=0;i<2;i++){
        acc2[j][i][0] += t.x; acc2[j][i][1] += t.y;
        acc2[j][i][2] += t.z; acc2[j][i][3] += t.w;
      }
    }
    const float* qb = qws + (size_t)b*HID + w*64 + lg*4;
    float4 q0 = *(const float4*)(qb);
    float4 q1 = *(const float4*)(qb + 16);
    float4 q2 = *(const float4*)(qb + 32);
    float4 q3 = *(const float4*)(qb + 48);
    #pragma unroll
    for (int i=0;i<2;i++){
      float mx = -1e30f;
      #pragma unroll
      for (int j=0;j<4;j++)
        mx = fmaxf(mx, fmaxf(fmaxf(acc2[j][i][0],acc2[j][i][1]),
                             fmaxf(acc2[j][i][2],acc2[j][i][3])));
      mx = fmaxf(mx, __shfl_xor(mx,16));
      mx = fmaxf(mx, __shfl_xor(mx,32));
      float se = 0.f, sq = 0.f;
      #define SMJ(J, QV) { \
        float e0=__expf(acc2[J][i][0]-mx), e1=__expf(acc2[J][i][1]-mx); \
        float e2=__expf(acc2[J][i][2]-mx), e3=__expf(acc2[J][i][3]-mx); \
        se += e0+e1+e2+e3; \
        sq += e0*QV.x + e1*QV.y + e2*QV.z + e3*QV.w; }
      SMJ(0, q0)
      SMJ(1, q1)
      SMJ(2, q2)
      SMJ(3, q3)
      #undef SMJ
      se += __shfl_xor(se,16); sq += __shfl_xor(sq,16);
      se += __shfl_xor(se,32); sq += __shfl_xor(sq,32);
      if (lg == 0){
        int row = (ih*2+i)*16 + lr;
        int t = tc*64 + row;
        float wt = (t == 0) ? (5.f/6.f) : ((t == T_-1) ? (1.f/6.f) : 1.f);
        float alpha = wt * sq / se;
        als[row][w] = alpha;
        __hip_bfloat16 ah = __float2bfloat16(alpha);
        float rem = alpha - __bfloat162float(ah);
        als_bt[0][w][row] = __bfloat16_as_ushort(ah);
        als_bt[1][w][row] = __bfloat16_as_ushort(__float2bfloat16(rem));
      }
    }
  }
  __syncthreads();

  // ---- phase 4: u = alpha^T @ H via MFMA (M=8 heads, N=64 cols/wave, K=64 rows) ----
  {
    f32x4 uacc[4];
    #pragma unroll
    for (int t=0;t<4;t++) uacc[t] = (f32x4){0.f,0.f,0.f,0.f};
    #pragma unroll
    for (int ks=0; ks<2; ks++){
      bf16x8 afh = *(const bf16x8*)&als_bt[0][lr][ks*32 + lg*8];
      bf16x8 afl = *(const bf16x8*)&als_bt[1][lr][ks*32 + lg*8];
      #pragma unroll
      for (int t=0;t<4;t++){
        int col = w*64 + t*16 + lr;
        int r0 = ks*32 + lg*8;
        uint4 bbu;
        {
          unsigned lo0 = *(const unsigned short*)(Hs + HSOFF(r0,   col));
          unsigned hi0 = *(const unsigned short*)(Hs + HSOFF(r0+1, col));
          unsigned lo1 = *(const unsigned short*)(Hs + HSOFF(r0+2, col));
          unsigned hi1 = *(const unsigned short*)(Hs + HSOFF(r0+3, col));
          unsigned lo2 = *(const unsigned short*)(Hs + HSOFF(r0+4, col));
          unsigned hi2 = *(const unsigned short*)(Hs + HSOFF(r0+5, col));
          unsigned lo3 = *(const unsigned short*)(Hs + HSOFF(r0+6, col));
          unsigned hi3 = *(const unsigned short*)(Hs + HSOFF(r0+7, col));
          bbu.x = lo0 | (hi0 << 16);
          bbu.y = lo1 | (hi1 << 16);
          bbu.z = lo2 | (hi2 << 16);
          bbu.w = lo3 | (hi3 << 16);
        }
        bf16x8 bvv = __builtin_bit_cast(bf16x8, bbu);
        uacc[t] = __builtin_amdgcn_mfma_f32_16x16x32_bf16(afh, bvv, uacc[t], 0,0,0);
        uacc[t] = __builtin_amdgcn_mfma_f32_16x16x32_bf16(afl, bvv, uacc[t], 0,0,0);
      }
    }
    if (lg < 2){
      #pragma unroll
      for (int t=0;t<4;t++){
        #pragma unroll
        for (int rr=0; rr<4; rr++){
          int h = lg*4 + rr;
          up[((((size_t)b*NH + h)*4 + tc)*HID) + w*64 + t*16 + lr] = uacc[t][rr];
        }
      }
    }
    float s = als[l][w];
    #pragma unroll
    for (int o=1;o<64;o<<=1) s += __shfl_xor(s,o);
    if (l == 0) Asp[(((size_t)b*NH + w)*4) + tc] = s;
  }
}

// ---------------- reduce partials: u_bf (bf16) and Asum ----------------
__global__ __launch_bounds__(256) void k_ured(
    const float* __restrict__ up, const float* __restrict__ Asp,
    __hip_bfloat16* __restrict__ u_bf, float* __restrict__ Asum)
{
  int bh = blockIdx.x, tid = threadIdx.x;
  size_t base = (size_t)bh*4*HID;
  float s0 = 0.f, s1 = 0.f;
  #pragma unroll
  for (int c=0;c<4;c++){
    s0 += up[base + (size_t)c*HID + 2*tid];
    s1 += up[base + (size_t)c*HID + 2*tid+1];
  }
  ((unsigned*)u_bf)[(size_t)bh*(HID/2) + tid] = pk2(s0, s1);
  if (tid == 0)
    Asum[bh] = Asp[(size_t)bh*4] + Asp[(size_t)bh*4+1] + Asp[(size_t)bh*4+2] + Asp[(size_t)bh*4+3];
}

// ---------------- k_tail: yh + Wo + LN + FF1 + FF2 + final, fully LDS-resident -------------
__global__ __launch_bounds__(512) void k_tail(
    const __hip_bfloat16* __restrict__ u_bf,   // (B,8,512)
    const __hip_bfloat16* __restrict__ Pv,
    const float* __restrict__ bv, const float* __restrict__ Asum,
    const float* __restrict__ yinit,
    const __hip_bfloat16* __restrict__ Po, const float* __restrict__ bo,
    const float* __restrict__ g_ff, const float* __restrict__ b_ff,
    const __hip_bfloat16* __restrict__ P1, const float* __restrict__ b1,
    const __hip_bfloat16* __restrict__ P2, const float* __restrict__ b2,
    const float* __restrict__ Wf, const float* __restrict__ bfv,
    float* __restrict__ out)
{
  int b0 = blockIdx.x*16;
  int tid = threadIdx.x;
  int w = tid >> 6, l = tid & 63, lr = l & 15, lg = l >> 4;
  __shared__ __align__(16) char Hs[16*1024];     // 16x512 bf16 swizzled (yh, then yln)
  __shared__ __align__(16) char A1[16*4096];     // 16x2048 bf16 swizzled (ff1 act)
  __shared__ float yoS[16][516];                 // f32 yo (then y2 in-place)
  __shared__ float red[16][8][2];
  __shared__ float ms2[16][2];
  f32x4 acc[4];

  // ---- phase 1: yh = u @ Wv_h^T + yinit + bv*Asum -> Hs ----
  #pragma unroll
  for (int j=0;j<4;j++) acc[j] = (f32x4){0.f,0.f,0.f,0.f};
  #pragma unroll
  for (int s = 0; s < 16; s++){
    bf16x8 af = *(const bf16x8*)(u_bf + ((size_t)(b0 + lr)*NH + w)*HID + s*32 + lg*8);
    const __hip_bfloat16* fb = Pv + (size_t)w*32768 + (size_t)s*2048 + l*8;
    #pragma unroll
    for (int j=0;j<4;j++){
      bf16x8 bfr = *(const bf16x8*)(fb + j*512);
      acc[j] = __builtin_amdgcn_mfma_f32_16x16x32_bf16(af, bfr, acc[j], 0,0,0);
    }
  }
  {
    float bvv[4];
    #pragma unroll
    for (int j=0;j<4;j++) bvv[j] = bv[w*64 + j*16 + lr];
    #pragma unroll
    for (int r=0;r<4;r++){
      int row = lg*4 + r;
      float As = Asum[(size_t)(b0+row)*NH + w];
      #pragma unroll
      for (int j=0;j<4;j++){
        int col = w*64 + j*16 + lr;
        float v = acc[j][r] + yinit[(size_t)(b0+row)*HID + col] + bvv[j]*As;
        *(unsigned short*)(Hs + HSOFF(row, col)) =
            __bfloat16_as_ushort(__float2bfloat16(v));
      }
    }
  }
  __syncthreads();

  // ---- phase 2: yo = yh @ Wo^T + bo -> yoS; LN -> yln overwrites Hs ----
  gemm512_pk16(Hs, Po + (size_t)w*32768, acc, l, lr, lg);
  {
    float bov[4], gv[4], bbv[4];
    #pragma unroll
    for (int j=0;j<4;j++){
      int col = w*64 + j*16 + lr;
      bov[j] = bo[col]; gv[j] = g_ff[col]; bbv[j] = b_ff[col];
    }
    #pragma unroll
    for (int r=0;r<4;r++){
      int row = lg*4 + r;
      float s = 0.f, s2 = 0.f;
      #pragma unroll
      for (int j=0;j<4;j++){
        float v = acc[j][r] + bov[j];
        yoS[row][w*64 + j*16 + lr] = v;
        s += v; s2 += v*v;
      }
      #pragma unroll
      for (int o=1;o<16;o<<=1){ s += __shfl_xor(s,o); s2 += __shfl_xor(s2,o); }
      if (lr == 0){ red[row][w][0] = s; red[row][w][1] = s2; }
    }
    __syncthreads();
    if (tid < 16){
      float S = 0.f, S2 = 0.f;
      #pragma unroll
      for (int k=0;k<8;k++){ S += red[tid][k][0]; S2 += red[tid][k][1]; }
      float m = S*(1.f/512.f), var = S2*(1.f/512.f) - m*m;
      ms2[tid][0] = m; ms2[tid][1] = rsqrtf(var + 1e-5f);
    }
    __syncthreads();
    #pragma unroll
    for (int r=0;r<4;r++){
      int row = lg*4 + r;
      float m = ms2[row][0], rs = ms2[row][1];
      #pragma unroll
      for (int j=0;j<4;j++){
        int col = w*64 + j*16 + lr;
        float v = (yoS[row][col] - m)*rs*gv[j] + bbv[j];
        *(unsigned short*)(Hs + HSOFF(row, col)) =
            __bfloat16_as_ushort(__float2bfloat16(v));
      }
    }
  }
  __syncthreads();

  // ---- phase 3: a1 = relu(yln @ W1^T + b1) -> A1 (wave w owns cols w*256..w*256+255) ----
  #pragma unroll
  for (int n0 = 0; n0 < 4; n0++){
    gemm512_pk16(Hs, P1 + (size_t)(w*4 + n0)*32768, acc, l, lr, lg);
    #pragma unroll
    for (int j=0;j<4;j++){
      int col = (w*4 + n0)*64 + j*16 + lr;
      float bc = b1[col];
      #pragma unroll
      for (int r=0;r<4;r++){
        int row = lg*4 + r;
        *(unsigned short*)(A1 + HS2OFF(row, col)) =
            __bfloat16_as_ushort(__float2bfloat16(fmaxf(acc[j][r] + bc, 0.f)));
      }
    }
  }
  __syncthreads();

  // ---- phase 4: y2 = a1 @ W2^T + b2 + yo (in-place into yoS) ----
  #pragma unroll
  for (int j=0;j<4;j++) acc[j] = (f32x4){0.f,0.f,0.f,0.f};
  #pragma unroll
  for (int s = 0; s < 64; s++){
    bf16x8 af = *(const bf16x8*)(A1 + HS2OFF(lr, s*32 + lg*8));
    const __hip_bfloat16* fb = P2 + (size_t)w*131072 + (size_t)s*2048 + l*8;
    #pragma unroll
    for (int j=0;j<4;j++){
      bf16x8 bfr = *(const bf16x8*)(fb + j*512);
      acc[j] = __builtin_amdgcn_mfma_f32_16x16x32_bf16(af, bfr, acc[j], 0,0,0);
    }
  }
  {
    float b2v[4];
    #pragma unroll
    for (int j=0;j<4;j++) b2v[j] = b2[w*64 + j*16 + lr];
    #pragma unroll
    for (int r=0;r<4;r++){
      int row = lg*4 + r;
      #pragma unroll
      for (int j=0;j<4;j++){
        int col = w*64 + j*16 + lr;
        yoS[row][col] = acc[j][r] + b2v[j] + yoS[row][col];
      }
    }
  }
  __syncthreads();

  // ---- phase 5: out = y2 @ Wf^T + bf ----
  {
    int pair = tid >> 1, half = tid & 1;
    if (pair < 16*OUTD){
      int row = pair / OUTD, oc = pair % OUTD;
      const float4* wr = (const float4*)(Wf + (size_t)oc*HID) + half*64;
      float sacc = 0.f;
      #pragma unroll 8
      for (int k4 = 0; k4 < 64; k4++){
        float4 a = wr[k4];
        int c = half*256 + k4*4;
        sacc += a.x*yoS[row][c] + a.y*yoS[row][c+1]
              + a.z*yoS[row][c+2] + a.w*yoS[row][c+3];
      }
      sacc += __shfl_xor(sacc, 1);
      if (half == 0) out[(size_t)(b0+row)*OUTD + oc] = bfv[oc] + sacc;
    }
  }
}

extern "C" void kernel_launch(void* const* d_in, const int* in_sizes, int n_in,
                              void* d_out, int out_size, void* d_ws, size_t ws_size,
                              hipStream_t stream)
{
  const float* initial = (const float*)d_in[0];
  const float* logsig  = (const float*)d_in[1];
  const float* Wi  = (const float*)d_in[2];  const float* bi  = (const float*)d_in[3];
  const float* Wip = (const float*)d_in[4];  const float* bip = (const float*)d_in[5];
  const float* g_in= (const float*)d_in[6];  const float* b_in= (const float*)d_in[7];
  const float* Wk  = (const float*)d_in[8];  const float* bk  = (const float*)d_in[9];
  const float* Wv  = (const float*)d_in[10]; const float* bv  = (const float*)d_in[11];
  const float* Wq  = (const float*)d_in[12]; const float* bq  = (const float*)d_in[13];
  const float* Wo  = (const float*)d_in[14]; const float* bo  = (const float*)d_in[15];
  const float* g_ff= (const float*)d_in[16]; const float* b_ff= (const float*)d_in[17];
  const float* W1  = (const float*)d_in[18]; const float* b1  = (const float*)d_in[19];
  const float* W2  = (const float*)d_in[20]; const float* b2  = (const float*)d_in[21];
  const float* Wf  = (const float*)d_in[22]; const float* bf  = (const float*)d_in[23];
  float* out = (float*)d_out;

  char* ws = (char*)d_ws;
  const size_t MB = 1<<20;
  float* qws   = (float*)(ws);                             // 512 KB
  float* yinit = (float*)(ws + 512*1024);                  // 512 KB
  __hip_bfloat16* u_bf = (__hip_bfloat16*)(ws + 3*MB);     // 2 MB
  float* Asum  = (float*)(ws + 5*MB);                      // 8 KB
  __hip_bfloat16* Pk  = (__hip_bfloat16*)(ws + 5*MB + 512*1024);  // 512 KB
  __hip_bfloat16* Pv  = (__hip_bfloat16*)(ws + 6*MB);      // 512 KB
  __hip_bfloat16* P1  = (__hip_bfloat16*)(ws + 6*MB + 512*1024);  // 2 MB
  __hip_bfloat16* P2  = (__hip_bfloat16*)(ws + 8*MB + 512*1024);  // 2 MB
  __hip_bfloat16* Po  = (__hip_bfloat16*)(ws + 13*MB);     // 512 KB
  __hip_bfloat16* Pip = (__hip_bfloat16*)(ws + 15*MB);     // 64 KB
  float* up    = (float*)(ws + 16*MB);                     // 16 MB
  float* Asp   = (float*)(ws + 33*MB);                     // 32 KB
  __hip_bfloat16* Pq  = (__hip_bfloat16*)(ws + 34*MB);     // 512 KB
  __hip_bfloat16* Pi  = (__hip_bfloat16*)(ws + 35*MB);     // 16 KB

  k_pack<<<dim3((PK_TOT + 255)/256), 256, 0, stream>>>(
      Wk, Wv, Wo, Wq, W1, W2, Wip, Wi,
      Pk, Pv, Po, Pq, P1, P2, Pip, Pi);
  k_pre<<<dim3(B_/16), 512, 0, stream>>>(initial, logsig, Pi, bi, Pip, bip,
                                         g_in, b_in, Pq, bq, Pk, bk, Pv, bv,
                                         qws, yinit);
  k_fused<<<dim3(B_, 4), 512, 0, stream>>>(logsig, Pip, bip, g_in, b_in,
                                           Pk, bk, qws, up, Asp);
  k_ured<<<dim3(B_*NH), 256, 0, stream>>>(up, Asp, u_bf, Asum);
  k_tail<<<dim3(B_/16), 512, 0, stream>>>(u_bf, Pv, bv, Asum, yinit,
                                          Po, bo, g_ff, b_ff,
                                          P1, b1, P2, b2, Wf, bf, out);
}

// Round 17
// 188.388 us; speedup vs baseline: 2.5533x; 2.5533x over previous
//
#include <hip/hip_runtime.h>
#include <hip/hip_bf16.h>
#include <math.h>

#define B_ 256
#define T_ 256
#define CIN 64
#define HID 512
#define NH 8
#define HD 64
#define FFD 2048
#define OUTD 10

typedef __bf16 bf16x8 __attribute__((ext_vector_type(8)));
typedef float f32x4 __attribute__((ext_vector_type(4)));

// swizzled LDS byte offset for a [rows x 512] bf16 tile (row stride 1024B)
#define HSOFF(r,c) (((r)<<10) + ((((c)<<1)) ^ ((((r)&7))<<4)))
// swizzled LDS byte offset for a [rows x 2048] bf16 tile (row stride 4096B)
#define HS2OFF(r,c) (((r)<<12) + ((((c)<<1)) ^ ((((r)&7))<<4)))

__device__ __forceinline__ float bf2f(unsigned u){
  union { unsigned i; float f; } c; c.i = u << 16; return c.f;
}
__device__ __forceinline__ unsigned pk2(float a, float b){
  return ((unsigned)__bfloat16_as_ushort(__float2bfloat16(a))) |
         (((unsigned)__bfloat16_as_ushort(__float2bfloat16(b))) << 16);
}

// ---------------- pack: f32 weight (N x K) -> bf16 MFMA-fragment order ----------------
__device__ __forceinline__ void pack_one(const float* __restrict__ W,
                                         __hip_bfloat16* __restrict__ P,
                                         const int K, int g){
  int row = g / (K/8), kg = g % (K/8);
  int k0 = kg*8;
  int n0 = row >> 6, j = (row >> 4) & 3, lr = row & 15;
  int s = k0 >> 5, lg = (k0 >> 3) & 3;
  int lane = lg*16 + lr;
  const float* src = W + (size_t)row*K + k0;
  float4 a = *(const float4*)src;
  float4 b = *(const float4*)(src+4);
  uint4 p = { pk2(a.x,a.y), pk2(a.z,a.w), pk2(b.x,b.y), pk2(b.z,b.w) };
  size_t off = ((((size_t)n0*(K>>5) + s)*4 + j)*64 + lane)*8;
  *(uint4*)(P + off) = p;
}

#define G_KV (HID*HID/8)   // 32768
#define G_FF (FFD*HID/8)   // 131072
#define G_IP (HID*CIN/8)   // 4096
#define G_I  (CIN*128/8)   // 1024
#define PK_TOT (4*G_KV + 2*G_FF + G_IP + G_I)
__global__ __launch_bounds__(256) void k_pack(
    const float* __restrict__ Wk, const float* __restrict__ Wv,
    const float* __restrict__ Wo, const float* __restrict__ Wq,
    const float* __restrict__ W1, const float* __restrict__ W2,
    const float* __restrict__ Wip, const float* __restrict__ Wi,
    __hip_bfloat16* __restrict__ Pk, __hip_bfloat16* __restrict__ Pv,
    __hip_bfloat16* __restrict__ Po, __hip_bfloat16* __restrict__ Pq,
    __hip_bfloat16* __restrict__ P1, __hip_bfloat16* __restrict__ P2,
    __hip_bfloat16* __restrict__ Pip, __hip_bfloat16* __restrict__ Pi)
{
  int g = blockIdx.x*256 + threadIdx.x;
  if (g < G_KV) { pack_one(Wk, Pk, HID, g); return; }  g -= G_KV;
  if (g < G_KV) { pack_one(Wv, Pv, HID, g); return; }  g -= G_KV;
  if (g < G_KV) { pack_one(Wo, Po, HID, g); return; }  g -= G_KV;
  if (g < G_KV) { pack_one(Wq, Pq, HID, g); return; }  g -= G_KV;
  if (g < G_FF) { pack_one(W1, P1, HID, g); return; }  g -= G_FF;
  if (g < G_FF) { pack_one(W2, P2, FFD, g); return; }  g -= G_FF;
  if (g < G_IP) { pack_one(Wip, Pip, CIN, g); return; }  g -= G_IP;
  if (g < G_I ) { pack_one(Wi, Pi, 128, g); }
}

// ---- building block (M=64): A(64x64 in Hs cols 0..64) @ Wip^T + LN -> Hs (64x512 bf16) ----
__device__ __forceinline__ void proj_ln(
    char* Hs, const __hip_bfloat16* __restrict__ Pip,
    const float* __restrict__ bip, const float* __restrict__ g_in,
    const float* __restrict__ b_in,
    float (*red)[8][2], float (*ms2)[2],
    int tid, int w, int l, int lr, int lg)
{
  f32x4 acc[4][4];
  #pragma unroll
  for (int i=0;i<4;i++)
    #pragma unroll
    for (int j=0;j<4;j++) acc[i][j] = (f32x4){0.f,0.f,0.f,0.f};
  #pragma unroll
  for (int s = 0; s < 2; s++){
    bf16x8 af[4], bfr[4];
    #pragma unroll
    for (int i=0;i<4;i++)
      af[i] = *(const bf16x8*)(Hs + HSOFF(i*16 + lr, s*32 + lg*8));
    const __hip_bfloat16* fb = Pip + ((size_t)(w*2 + s)*4)*512 + l*8;
    #pragma unroll
    for (int j=0;j<4;j++)
      bfr[j] = *(const bf16x8*)(fb + j*512);
    #pragma unroll
    for (int i=0;i<4;i++)
      #pragma unroll
      for (int j=0;j<4;j++)
        acc[i][j] = __builtin_amdgcn_mfma_f32_16x16x32_bf16(af[i], bfr[j], acc[i][j], 0,0,0);
  }
  float bipv[4], gv[4], bbv[4];
  #pragma unroll
  for (int j=0;j<4;j++){
    int col = w*64 + j*16 + lr;
    bipv[j] = bip[col]; gv[j] = g_in[col]; bbv[j] = b_in[col];
  }
  #pragma unroll
  for (int i=0;i<4;i++){
    #pragma unroll
    for (int r=0;r<4;r++){
      float s = 0.f, s2 = 0.f;
      #pragma unroll
      for (int j=0;j<4;j++){ float v = acc[i][j][r] + bipv[j]; s += v; s2 += v*v; }
      #pragma unroll
      for (int o=1;o<16;o<<=1){ s += __shfl_xor(s,o); s2 += __shfl_xor(s2,o); }
      if (lr == 0){ int row = i*16 + lg*4 + r; red[row][w][0] = s; red[row][w][1] = s2; }
    }
  }
  __syncthreads();
  if (tid < 64){
    float S = 0.f, S2 = 0.f;
    #pragma unroll
    for (int k=0;k<8;k++){ S += red[tid][k][0]; S2 += red[tid][k][1]; }
    float m = S*(1.f/512.f), var = S2*(1.f/512.f) - m*m;
    ms2[tid][0] = m; ms2[tid][1] = rsqrtf(var + 1e-5f);
  }
  __syncthreads();
  #pragma unroll
  for (int i=0;i<4;i++){
    #pragma unroll
    for (int r=0;r<4;r++){
      int row = i*16 + lg*4 + r;
      float m = ms2[row][0], rs = ms2[row][1];
      #pragma unroll
      for (int j=0;j<4;j++){
        int col = w*64 + j*16 + lr;
        float v = (acc[i][j][r] + bipv[j] - m)*rs*gv[j] + bbv[j];
        *(unsigned short*)(Hs + HSOFF(row, col)) =
            __bfloat16_as_ushort(__float2bfloat16(v));
      }
    }
  }
  __syncthreads();
}

// ---- building block (M=64): acc = Hs(64x512) @ P^T (K=512, packed, n0 pre-applied) ----
__device__ __forceinline__ void gemm512_pk(
    const char* Hs, const __hip_bfloat16* __restrict__ Pm,
    f32x4 acc[4][4], int l, int lr, int lg)
{
  #pragma unroll
  for (int i=0;i<4;i++)
    #pragma unroll
    for (int j=0;j<4;j++) acc[i][j] = (f32x4){0.f,0.f,0.f,0.f};
  #pragma unroll
  for (int s = 0; s < 16; s++){
    bf16x8 af[4], bfr[4];
    #pragma unroll
    for (int i=0;i<4;i++)
      af[i] = *(const bf16x8*)(Hs + HSOFF(i*16 + lr, s*32 + lg*8));
    const __hip_bfloat16* fb = Pm + (size_t)s*2048 + l*8;
    #pragma unroll
    for (int j=0;j<4;j++)
      bfr[j] = *(const bf16x8*)(fb + j*512);
    #pragma unroll
    for (int i=0;i<4;i++)
      #pragma unroll
      for (int j=0;j<4;j++)
        acc[i][j] = __builtin_amdgcn_mfma_f32_16x16x32_bf16(af[i], bfr[j], acc[i][j], 0,0,0);
  }
}

// ---- building block (M=16): A(16x64 in Hs cols 0..64) @ Wip^T + LN -> Hs (16x512 bf16) ----
__device__ __forceinline__ void proj_ln16(
    char* Hs, const __hip_bfloat16* __restrict__ Pip,
    const float* __restrict__ bip, const float* __restrict__ g_in,
    const float* __restrict__ b_in,
    float (*red)[8][2], float (*ms2)[2],
    int tid, int w, int l, int lr, int lg)
{
  f32x4 acc[4];
  #pragma unroll
  for (int j=0;j<4;j++) acc[j] = (f32x4){0.f,0.f,0.f,0.f};
  #pragma unroll
  for (int s = 0; s < 2; s++){
    bf16x8 af = *(const bf16x8*)(Hs + HSOFF(lr, s*32 + lg*8));
    const __hip_bfloat16* fb = Pip + ((size_t)(w*2 + s)*4)*512 + l*8;
    #pragma unroll
    for (int j=0;j<4;j++){
      bf16x8 bfr = *(const bf16x8*)(fb + j*512);
      acc[j] = __builtin_amdgcn_mfma_f32_16x16x32_bf16(af, bfr, acc[j], 0,0,0);
    }
  }
  float bipv[4], gv[4], bbv[4];
  #pragma unroll
  for (int j=0;j<4;j++){
    int col = w*64 + j*16 + lr;
    bipv[j] = bip[col]; gv[j] = g_in[col]; bbv[j] = b_in[col];
  }
  #pragma unroll
  for (int r=0;r<4;r++){
    float s = 0.f, s2 = 0.f;
    #pragma unroll
    for (int j=0;j<4;j++){ float v = acc[j][r] + bipv[j]; s += v; s2 += v*v; }
    #pragma unroll
    for (int o=1;o<16;o<<=1){ s += __shfl_xor(s,o); s2 += __shfl_xor(s2,o); }
    if (lr == 0){ int row = lg*4 + r; red[row][w][0] = s; red[row][w][1] = s2; }
  }
  __syncthreads();
  if (tid < 16){
    float S = 0.f, S2 = 0.f;
    #pragma unroll
    for (int k=0;k<8;k++){ S += red[tid][k][0]; S2 += red[tid][k][1]; }
    float m = S*(1.f/512.f), var = S2*(1.f/512.f) - m*m;
    ms2[tid][0] = m; ms2[tid][1] = rsqrtf(var + 1e-5f);
  }
  __syncthreads();
  #pragma unroll
  for (int r=0;r<4;r++){
    int row = lg*4 + r;
    float m = ms2[row][0], rs = ms2[row][1];
    #pragma unroll
    for (int j=0;j<4;j++){
      int col = w*64 + j*16 + lr;
      float v = (acc[j][r] + bipv[j] - m)*rs*gv[j] + bbv[j];
      *(unsigned short*)(Hs + HSOFF(row, col)) =
          __bfloat16_as_ushort(__float2bfloat16(v));
    }
  }
  __syncthreads();
}

// ---- building block (M=16): acc = Hs(16x512) @ P^T (K=512, packed, n0 pre-applied) ----
__device__ __forceinline__ void gemm512_pk16(
    const char* Hs, const __hip_bfloat16* __restrict__ Pm,
    f32x4 acc[4], int l, int lr, int lg)
{
  #pragma unroll
  for (int j=0;j<4;j++) acc[j] = (f32x4){0.f,0.f,0.f,0.f};
  #pragma unroll
  for (int s = 0; s < 16; s++){
    bf16x8 af = *(const bf16x8*)(Hs + HSOFF(lr, s*32 + lg*8));
    const __hip_bfloat16* fb = Pm + (size_t)s*2048 + l*8;
    #pragma unroll
    for (int j=0;j<4;j++){
      bf16x8 bfr = *(const bf16x8*)(fb + j*512);
      acc[j] = __builtin_amdgcn_mfma_f32_16x16x32_bf16(af, bfr, acc[j], 0,0,0);
    }
  }
}

// ---------------- k_pre: batched init path (q, yinit), 16 blocks x 16 batch rows ----------
__global__ __launch_bounds__(512) void k_pre(
    const float* __restrict__ initial, const float* __restrict__ logsig,
    const __hip_bfloat16* __restrict__ Pi,  const float* __restrict__ bi,
    const __hip_bfloat16* __restrict__ Pip, const float* __restrict__ bip,
    const float* __restrict__ g_in, const float* __restrict__ b_in,
    const __hip_bfloat16* __restrict__ Pq, const float* __restrict__ bq,
    const __hip_bfloat16* __restrict__ Pk, const float* __restrict__ bk,
    const __hip_bfloat16* __restrict__ Pv, const float* __restrict__ bv,
    float* __restrict__ qout, float* __restrict__ yinit)
{
  int b0 = blockIdx.x*16;
  int tid = threadIdx.x;
  int w = tid >> 6, l = tid & 63, lr = l & 15, lg = l >> 4;
  __shared__ __align__(16) char Hs[16*1024];
  __shared__ float red[16][8][2];
  __shared__ float ms2[16][2];
  __shared__ float salS[16][8];
  f32x4 acc[4];

  // ---- phase A: stage xlast (16 rows x 64 cols) -> Hs; hq = LN(x @ Wip^T) ----
  {
    int row = tid >> 5, c = (tid & 31)*2;
    const float* s = logsig + ((size_t)(b0+row)*T_ + (T_-1))*CIN + c;
    float2 a = *(const float2*)s;
    *(unsigned*)(Hs + HSOFF(row, c)) = pk2(a.x, a.y);
  }
  __syncthreads();
  proj_ln16(Hs, Pip, bip, g_in, b_in, red, ms2, tid, w, l, lr, lg);

  // ---- phase B: q = softmax_h(hq @ Wq_h^T + bq), kept in registers ----
  float qreg[4][4];   // [j][r]
  gemm512_pk16(Hs, Pq + (size_t)w*32768, acc, l, lr, lg);
  {
    float bqv[4];
    #pragma unroll
    for (int j=0;j<4;j++) bqv[j] = bq[w*64 + j*16 + lr];
    #pragma unroll
    for (int r=0;r<4;r++){
      float v0 = acc[0][r]+bqv[0], v1 = acc[1][r]+bqv[1];
      float v2 = acc[2][r]+bqv[2], v3 = acc[3][r]+bqv[3];
      float mx = fmaxf(fmaxf(v0,v1),fmaxf(v2,v3));
      #pragma unroll
      for (int o=1;o<16;o<<=1) mx = fmaxf(mx, __shfl_xor(mx,o));
      float e0=__expf(v0-mx), e1=__expf(v1-mx), e2=__expf(v2-mx), e3=__expf(v3-mx);
      float se = e0+e1+e2+e3;
      #pragma unroll
      for (int o=1;o<16;o<<=1) se += __shfl_xor(se,o);
      float inv = 1.f/se;
      qreg[0][r]=e0*inv; qreg[1][r]=e1*inv; qreg[2][r]=e2*inv; qreg[3][r]=e3*inv;
      int row = lg*4 + r;
      size_t base = (size_t)(b0+row)*HID + w*64 + lr;
      qout[base +  0] = qreg[0][r]; qout[base + 16] = qreg[1][r];
      qout[base + 32] = qreg[2][r]; qout[base + 48] = qreg[3][r];
    }
  }
  __syncthreads();

  // ---- phase C: stage initial (16x128) -> Hs cols 64..192; ip = initial@Wi^T+bi -> cols 0..64
  {
    int row = tid >> 5, c = (tid & 31)*4;
    const float* s = initial + (size_t)(b0+row)*128 + c;
    float4 a = *(const float4*)s;
    uint2 p = { pk2(a.x,a.y), pk2(a.z,a.w) };
    *(uint2*)(Hs + HSOFF(row, 64 + c)) = p;
  }
  __syncthreads();
  if (w < 4){
    f32x4 a2 = (f32x4){0.f,0.f,0.f,0.f};
    #pragma unroll
    for (int s = 0; s < 4; s++){
      bf16x8 af = *(const bf16x8*)(Hs + HSOFF(lr, 64 + s*32 + lg*8));
      bf16x8 bfr = *(const bf16x8*)(Pi + ((size_t)s*4 + w)*512 + l*8);
      a2 = __builtin_amdgcn_mfma_f32_16x16x32_bf16(af, bfr, a2, 0,0,0);
    }
    float bic = bi[w*16 + lr];
    #pragma unroll
    for (int r=0;r<4;r++){
      *(unsigned short*)(Hs + HSOFF(lg*4 + r, w*16 + lr)) =
          __bfloat16_as_ushort(__float2bfloat16(a2[r] + bic));
    }
  }
  __syncthreads();

  // ---- phase D: h0 = LN(ip @ Wip^T) -> Hs ----
  proj_ln16(Hs, Pip, bip, g_in, b_in, red, ms2, tid, w, l, lr, lg);

  // ---- phase E: k0 scores; sal = softmax(k0).q ----
  gemm512_pk16(Hs, Pk + (size_t)w*32768, acc, l, lr, lg);
  {
    float bkv[4];
    #pragma unroll
    for (int j=0;j<4;j++) bkv[j] = bk[w*64 + j*16 + lr];
    #pragma unroll
    for (int r=0;r<4;r++){
      float v0 = acc[0][r]+bkv[0], v1 = acc[1][r]+bkv[1];
      float v2 = acc[2][r]+bkv[2], v3 = acc[3][r]+bkv[3];
      float mx = fmaxf(fmaxf(v0,v1),fmaxf(v2,v3));
      #pragma unroll
      for (int o=1;o<16;o<<=1) mx = fmaxf(mx, __shfl_xor(mx,o));
      float e0=__expf(v0-mx), e1=__expf(v1-mx), e2=__expf(v2-mx), e3=__expf(v3-mx);
      float se = e0+e1+e2+e3;
      float sq = e0*qreg[0][r]+e1*qreg[1][r]+e2*qreg[2][r]+e3*qreg[3][r];
      #pragma unroll
      for (int o=1;o<16;o<<=1){ se += __shfl_xor(se,o); sq += __shfl_xor(sq,o); }
      if (lr == 0) salS[lg*4 + r][w] = sq/se;
    }
  }
  __syncthreads();

  // ---- phase F: v0; yinit = sal * v0 ----
  gemm512_pk16(Hs, Pv + (size_t)w*32768, acc, l, lr, lg);
  {
    float bvv[4];
    #pragma unroll
    for (int j=0;j<4;j++) bvv[j] = bv[w*64 + j*16 + lr];
    #pragma unroll
    for (int r=0;r<4;r++){
      int row = lg*4 + r;
      float s = salS[row][w];
      size_t base = (size_t)(b0+row)*HID + w*64 + lr;
      yinit[base +  0] = s*(acc[0][r]+bvv[0]);
      yinit[base + 16] = s*(acc[1][r]+bvv[1]);
      yinit[base + 32] = s*(acc[2][r]+bvv[2]);
      yinit[base + 48] = s*(acc[3][r]+bvv[3]);
    }
  }
}

// ---------------- FUSED kernel (r11 structure): hln + score + softmax.q + MFMA partial-u ---
__global__ __launch_bounds__(512, 4) void k_fused(
    const float* __restrict__ logsig,
    const __hip_bfloat16* __restrict__ Pip,
    const float* __restrict__ bip,
    const float* __restrict__ g_in, const float* __restrict__ b_in,
    const __hip_bfloat16* __restrict__ Pk,
    const float* __restrict__ bk,
    const float* __restrict__ qws,             // (B,512)
    float* __restrict__ up,                    // (B,NH,4,512) f32 partial u
    float* __restrict__ Asp)                   // (B,NH,4) partial alpha-sum
{
  int b = blockIdx.x, tc = blockIdx.y;
  int tid = threadIdx.x;
  int w = tid >> 6, l = tid & 63, lr = l & 15, lg = l >> 4;
  __shared__ __align__(16) char Hs[64*1024];     // 64 rows x 512 bf16, swizzled
  __shared__ float red[64][8][2];
  __shared__ float ms2[64][2];
  __shared__ float als[64][8];
  __shared__ unsigned short als_bt[2][16][64];   // alpha^T bf16 hi/lo (rows 8-15 unused)

  // ---- stage logsig x-tile (64x64 f32 -> bf16) into Hs cols 0..64 ----
  {
    int row = tid >> 3, cc = (tid & 7)*8;
    const float* srow = logsig + ((size_t)b*T_ + tc*64 + row)*CIN + cc;
    float4 a = *(const float4*)(srow);
    float4 c = *(const float4*)(srow+4);
    uint4 p = { pk2(a.x,a.y), pk2(a.z,a.w), pk2(c.x,c.y), pk2(c.z,c.w) };
    *(uint4*)(Hs + HSOFF(row, cc)) = p;
  }
  __syncthreads();

  // ---- phase 1: Hln = LN(x @ Wip^T + bip) ----
  proj_ln(Hs, Pip, bip, g_in, b_in, red, ms2, tid, w, l, lr, lg);

  // ---- phase 2: scores S = Hln @ Wk_h^T (wave w = head w), A from LDS ----
  f32x4 acc[4][4];
  gemm512_pk(Hs, Pk + (size_t)w*32768, acc, l, lr, lg);

  // ---- phase 3: per-row softmax over head cols, dot q, RK4 weight -> als (+bf16 hi/lo T) ----
  {
    float bkv[4], qv[4];
    #pragma unroll
    for (int j=0;j<4;j++){
      bkv[j] = bk[w*64 + j*16 + lr];
      qv[j]  = qws[(size_t)b*HID + w*64 + j*16 + lr];
    }
    #pragma unroll
    for (int i=0;i<4;i++){
      #pragma unroll
      for (int r=0;r<4;r++){
        float v0 = acc[i][0][r]+bkv[0], v1 = acc[i][1][r]+bkv[1];
        float v2 = acc[i][2][r]+bkv[2], v3 = acc[i][3][r]+bkv[3];
        float mx = fmaxf(fmaxf(v0,v1),fmaxf(v2,v3));
        #pragma unroll
        for (int o=1;o<16;o<<=1) mx = fmaxf(mx, __shfl_xor(mx,o));
        float e0=__expf(v0-mx), e1=__expf(v1-mx), e2=__expf(v2-mx), e3=__expf(v3-mx);
        float se = e0+e1+e2+e3;
        float sq = e0*qv[0]+e1*qv[1]+e2*qv[2]+e3*qv[3];
        #pragma unroll
        for (int o=1;o<16;o<<=1){ se += __shfl_xor(se,o); sq += __shfl_xor(sq,o); }
        if (lr == 0){
          int row = i*16 + lg*4 + r;
          int t = tc*64 + row;
          float wt = (t == 0) ? (5.f/6.f) : ((t == T_-1) ? (1.f/6.f) : 1.f);
          float alpha = wt * sq / se;
          als[row][w] = alpha;
          __hip_bfloat16 ah = __float2bfloat16(alpha);
          float rem = alpha - __bfloat162float(ah);
          als_bt[0][w][row] = __bfloat16_as_ushort(ah);
          als_bt[1][w][row] = __bfloat16_as_ushort(__float2bfloat16(rem));
        }
      }
    }
  }
  __syncthreads();

  // ---- phase 4: u = alpha^T @ H via MFMA (M=8 heads, N=64 cols/wave, K=64 rows) ----
  {
    f32x4 uacc[4];
    #pragma unroll
    for (int t=0;t<4;t++) uacc[t] = (f32x4){0.f,0.f,0.f,0.f};
    #pragma unroll
    for (int ks=0; ks<2; ks++){
      bf16x8 afh = *(const bf16x8*)&als_bt[0][lr][ks*32 + lg*8];
      bf16x8 afl = *(const bf16x8*)&als_bt[1][lr][ks*32 + lg*8];
      #pragma unroll
      for (int t=0;t<4;t++){
        int col = w*64 + t*16 + lr;
        int r0 = ks*32 + lg*8;
        uint4 bbu;
        {
          unsigned lo0 = *(const unsigned short*)(Hs + HSOFF(r0,   col));
          unsigned hi0 = *(const unsigned short*)(Hs + HSOFF(r0+1, col));
          unsigned lo1 = *(const unsigned short*)(Hs + HSOFF(r0+2, col));
          unsigned hi1 = *(const unsigned short*)(Hs + HSOFF(r0+3, col));
          unsigned lo2 = *(const unsigned short*)(Hs + HSOFF(r0+4, col));
          unsigned hi2 = *(const unsigned short*)(Hs + HSOFF(r0+5, col));
          unsigned lo3 = *(const unsigned short*)(Hs + HSOFF(r0+6, col));
          unsigned hi3 = *(const unsigned short*)(Hs + HSOFF(r0+7, col));
          bbu.x = lo0 | (hi0 << 16);
          bbu.y = lo1 | (hi1 << 16);
          bbu.z = lo2 | (hi2 << 16);
          bbu.w = lo3 | (hi3 << 16);
        }
        bf16x8 bvv = __builtin_bit_cast(bf16x8, bbu);
        uacc[t] = __builtin_amdgcn_mfma_f32_16x16x32_bf16(afh, bvv, uacc[t], 0,0,0);
        uacc[t] = __builtin_amdgcn_mfma_f32_16x16x32_bf16(afl, bvv, uacc[t], 0,0,0);
      }
    }
    if (lg < 2){
      #pragma unroll
      for (int t=0;t<4;t++){
        #pragma unroll
        for (int rr=0; rr<4; rr++){
          int h = lg*4 + rr;
          up[((((size_t)b*NH + h)*4 + tc)*HID) + w*64 + t*16 + lr] = uacc[t][rr];
        }
      }
    }
    float s = als[l][w];
    #pragma unroll
    for (int o=1;o<64;o<<=1) s += __shfl_xor(s,o);
    if (l == 0) Asp[(((size_t)b*NH + w)*4) + tc] = s;
  }
}

// ---------------- reduce partials: u_bf (bf16) and Asum ----------------
__global__ __launch_bounds__(256) void k_ured(
    const float* __restrict__ up, const float* __restrict__ Asp,
    __hip_bfloat16* __restrict__ u_bf, float* __restrict__ Asum)
{
  int bh = blockIdx.x, tid = threadIdx.x;
  size_t base = (size_t)bh*4*HID;
  float s0 = 0.f, s1 = 0.f;
  #pragma unroll
  for (int c=0;c<4;c++){
    s0 += up[base + (size_t)c*HID + 2*tid];
    s1 += up[base + (size_t)c*HID + 2*tid+1];
  }
  ((unsigned*)u_bf)[(size_t)bh*(HID/2) + tid] = pk2(s0, s1);
  if (tid == 0)
    Asum[bh] = Asp[(size_t)bh*4] + Asp[(size_t)bh*4+1] + Asp[(size_t)bh*4+2] + Asp[(size_t)bh*4+3];
}

// ---------------- k_tail: yh + Wo + LN + FF1 + FF2 + final, fully LDS-resident -------------
__global__ __launch_bounds__(512) void k_tail(
    const __hip_bfloat16* __restrict__ u_bf,   // (B,8,512)
    const __hip_bfloat16* __restrict__ Pv,
    const float* __restrict__ bv, const float* __restrict__ Asum,
    const float* __restrict__ yinit,
    const __hip_bfloat16* __restrict__ Po, const float* __restrict__ bo,
    const float* __restrict__ g_ff, const float* __restrict__ b_ff,
    const __hip_bfloat16* __restrict__ P1, const float* __restrict__ b1,
    const __hip_bfloat16* __restrict__ P2, const float* __restrict__ b2,
    const float* __restrict__ Wf, const float* __restrict__ bfv,
    float* __restrict__ out)
{
  int b0 = blockIdx.x*16;
  int tid = threadIdx.x;
  int w = tid >> 6, l = tid & 63, lr = l & 15, lg = l >> 4;
  __shared__ __align__(16) char Hs[16*1024];     // 16x512 bf16 swizzled (yh, then yln)
  __shared__ __align__(16) char A1[16*4096];     // 16x2048 bf16 swizzled (ff1 act)
  __shared__ float yoS[16][516];                 // f32 yo (then y2 in-place)
  __shared__ float red[16][8][2];
  __shared__ float ms2[16][2];
  f32x4 acc[4];

  // ---- phase 1: yh = u @ Wv_h^T + yinit + bv*Asum -> Hs ----
  #pragma unroll
  for (int j=0;j<4;j++) acc[j] = (f32x4){0.f,0.f,0.f,0.f};
  #pragma unroll
  for (int s = 0; s < 16; s++){
    bf16x8 af = *(const bf16x8*)(u_bf + ((size_t)(b0 + lr)*NH + w)*HID + s*32 + lg*8);
    const __hip_bfloat16* fb = Pv + (size_t)w*32768 + (size_t)s*2048 + l*8;
    #pragma unroll
    for (int j=0;j<4;j++){
      bf16x8 bfr = *(const bf16x8*)(fb + j*512);
      acc[j] = __builtin_amdgcn_mfma_f32_16x16x32_bf16(af, bfr, acc[j], 0,0,0);
    }
  }
  {
    float bvv[4];
    #pragma unroll
    for (int j=0;j<4;j++) bvv[j] = bv[w*64 + j*16 + lr];
    #pragma unroll
    for (int r=0;r<4;r++){
      int row = lg*4 + r;
      float As = Asum[(size_t)(b0+row)*NH + w];
      #pragma unroll
      for (int j=0;j<4;j++){
        int col = w*64 + j*16 + lr;
        float v = acc[j][r] + yinit[(size_t)(b0+row)*HID + col] + bvv[j]*As;
        *(unsigned short*)(Hs + HSOFF(row, col)) =
            __bfloat16_as_ushort(__float2bfloat16(v));
      }
    }
  }
  __syncthreads();

  // ---- phase 2: yo = yh @ Wo^T + bo -> yoS; LN -> yln overwrites Hs ----
  gemm512_pk16(Hs, Po + (size_t)w*32768, acc, l, lr, lg);
  {
    float bov[4], gv[4], bbv[4];
    #pragma unroll
    for (int j=0;j<4;j++){
      int col = w*64 + j*16 + lr;
      bov[j] = bo[col]; gv[j] = g_ff[col]; bbv[j] = b_ff[col];
    }
    #pragma unroll
    for (int r=0;r<4;r++){
      int row = lg*4 + r;
      float s = 0.f, s2 = 0.f;
      #pragma unroll
      for (int j=0;j<4;j++){
        float v = acc[j][r] + bov[j];
        yoS[row][w*64 + j*16 + lr] = v;
        s += v; s2 += v*v;
      }
      #pragma unroll
      for (int o=1;o<16;o<<=1){ s += __shfl_xor(s,o); s2 += __shfl_xor(s2,o); }
      if (lr == 0){ red[row][w][0] = s; red[row][w][1] = s2; }
    }
    __syncthreads();
    if (tid < 16){
      float S = 0.f, S2 = 0.f;
      #pragma unroll
      for (int k=0;k<8;k++){ S += red[tid][k][0]; S2 += red[tid][k][1]; }
      float m = S*(1.f/512.f), var = S2*(1.f/512.f) - m*m;
      ms2[tid][0] = m; ms2[tid][1] = rsqrtf(var + 1e-5f);
    }
    __syncthreads();
    #pragma unroll
    for (int r=0;r<4;r++){
      int row = lg*4 + r;
      float m = ms2[row][0], rs = ms2[row][1];
      #pragma unroll
      for (int j=0;j<4;j++){
        int col = w*64 + j*16 + lr;
        float v = (yoS[row][col] - m)*rs*gv[j] + bbv[j];
        *(unsigned short*)(Hs + HSOFF(row, col)) =
            __bfloat16_as_ushort(__float2bfloat16(v));
      }
    }
  }
  __syncthreads();

  // ---- phase 3: a1 = relu(yln @ W1^T + b1) -> A1 (wave w owns cols w*256..w*256+255) ----
  #pragma unroll
  for (int n0 = 0; n0 < 4; n0++){
    gemm512_pk16(Hs, P1 + (size_t)(w*4 + n0)*32768, acc, l, lr, lg);
    #pragma unroll
    for (int j=0;j<4;j++){
      int col = (w*4 + n0)*64 + j*16 + lr;
      float bc = b1[col];
      #pragma unroll
      for (int r=0;r<4;r++){
        int row = lg*4 + r;
        *(unsigned short*)(A1 + HS2OFF(row, col)) =
            __bfloat16_as_ushort(__float2bfloat16(fmaxf(acc[j][r] + bc, 0.f)));
      }
    }
  }
  __syncthreads();

  // ---- phase 4: y2 = a1 @ W2^T + b2 + yo (in-place into yoS) ----
  #pragma unroll
  for (int j=0;j<4;j++) acc[j] = (f32x4){0.f,0.f,0.f,0.f};
  #pragma unroll
  for (int s = 0; s < 64; s++){
    bf16x8 af = *(const bf16x8*)(A1 + HS2OFF(lr, s*32 + lg*8));
    const __hip_bfloat16* fb = P2 + (size_t)w*131072 + (size_t)s*2048 + l*8;
    #pragma unroll
    for (int j=0;j<4;j++){
      bf16x8 bfr = *(const bf16x8*)(fb + j*512);
      acc[j] = __builtin_amdgcn_mfma_f32_16x16x32_bf16(af, bfr, acc[j], 0,0,0);
    }
  }
  {
    float b2v[4];
    #pragma unroll
    for (int j=0;j<4;j++) b2v[j] = b2[w*64 + j*16 + lr];
    #pragma unroll
    for (int r=0;r<4;r++){
      int row = lg*4 + r;
      #pragma unroll
      for (int j=0;j<4;j++){
        int col = w*64 + j*16 + lr;
        yoS[row][col] = acc[j][r] + b2v[j] + yoS[row][col];
      }
    }
  }
  __syncthreads();

  // ---- phase 5: out = y2 @ Wf^T + bf ----
  {
    int pair = tid >> 1, half = tid & 1;
    if (pair < 16*OUTD){
      int row = pair / OUTD, oc = pair % OUTD;
      const float4* wr = (const float4*)(Wf + (size_t)oc*HID) + half*64;
      float sacc = 0.f;
      #pragma unroll 8
      for (int k4 = 0; k4 < 64; k4++){
        float4 a = wr[k4];
        int c = half*256 + k4*4;
        sacc += a.x*yoS[row][c] + a.y*yoS[row][c+1]
              + a.z*yoS[row][c+2] + a.w*yoS[row][c+3];
      }
      sacc += __shfl_xor(sacc, 1);
      if (half == 0) out[(size_t)(b0+row)*OUTD + oc] = bfv[oc] + sacc;
    }
  }
}

extern "C" void kernel_launch(void* const* d_in, const int* in_sizes, int n_in,
                              void* d_out, int out_size, void* d_ws, size_t ws_size,
                              hipStream_t stream)
{
  const float* initial = (const float*)d_in[0];
  const float* logsig  = (const float*)d_in[1];
  const float* Wi  = (const float*)d_in[2];  const float* bi  = (const float*)d_in[3];
  const float* Wip = (const float*)d_in[4];  const float* bip = (const float*)d_in[5];
  const float* g_in= (const float*)d_in[6];  const float* b_in= (const float*)d_in[7];
  const float* Wk  = (const float*)d_in[8];  const float* bk  = (const float*)d_in[9];
  const float* Wv  = (const float*)d_in[10]; const float* bv  = (const float*)d_in[11];
  const float* Wq  = (const float*)d_in[12]; const float* bq  = (const float*)d_in[13];
  const float* Wo  = (const float*)d_in[14]; const float* bo  = (const float*)d_in[15];
  const float* g_ff= (const float*)d_in[16]; const float* b_ff= (const float*)d_in[17];
  const float* W1  = (const float*)d_in[18]; const float* b1  = (const float*)d_in[19];
  const float* W2  = (const float*)d_in[20]; const float* b2  = (const float*)d_in[21];
  const float* Wf  = (const float*)d_in[22]; const float* bf  = (const float*)d_in[23];
  float* out = (float*)d_out;

  char* ws = (char*)d_ws;
  const size_t MB = 1<<20;
  float* qws   = (float*)(ws);                             // 512 KB
  float* yinit = (float*)(ws + 512*1024);                  // 512 KB
  __hip_bfloat16* u_bf = (__hip_bfloat16*)(ws + 3*MB);     // 2 MB
  float* Asum  = (float*)(ws + 5*MB);                      // 8 KB
  __hip_bfloat16* Pk  = (__hip_bfloat16*)(ws + 5*MB + 512*1024);  // 512 KB
  __hip_bfloat16* Pv  = (__hip_bfloat16*)(ws + 6*MB);      // 512 KB
  __hip_bfloat16* P1  = (__hip_bfloat16*)(ws + 6*MB + 512*1024);  // 2 MB
  __hip_bfloat16* P2  = (__hip_bfloat16*)(ws + 8*MB + 512*1024);  // 2 MB
  __hip_bfloat16* Po  = (__hip_bfloat16*)(ws + 13*MB);     // 512 KB
  __hip_bfloat16* Pip = (__hip_bfloat16*)(ws + 15*MB);     // 64 KB
  float* up    = (float*)(ws + 16*MB);                     // 16 MB
  float* Asp   = (float*)(ws + 33*MB);                     // 32 KB
  __hip_bfloat16* Pq  = (__hip_bfloat16*)(ws + 34*MB);     // 512 KB
  __hip_bfloat16* Pi  = (__hip_bfloat16*)(ws + 35*MB);     // 16 KB

  k_pack<<<dim3((PK_TOT + 255)/256), 256, 0, stream>>>(
      Wk, Wv, Wo, Wq, W1, W2, Wip, Wi,
      Pk, Pv, Po, Pq, P1, P2, Pip, Pi);
  k_pre<<<dim3(B_/16), 512, 0, stream>>>(initial, logsig, Pi, bi, Pip, bip,
                                         g_in, b_in, Pq, bq, Pk, bk, Pv, bv,
                                         qws, yinit);
  k_fused<<<dim3(B_, 4), 512, 0, stream>>>(logsig, Pip, bip, g_in, b_in,
                                           Pk, bk, qws, up, Asp);
  k_ured<<<dim3(B_*NH), 256, 0, stream>>>(up, Asp, u_bf, Asum);
  k_tail<<<dim3(B_/16), 512, 0, stream>>>(u_bf, Pv, bv, Asum, yinit,
                                          Po, bo, g_ff, b_ff,
                                          P1, b1, P2, b2, Wf, bf, out);
}

// Round 18
// 160.303 us; speedup vs baseline: 3.0006x; 1.1752x over previous
//
#include <hip/hip_runtime.h>
#include <hip/hip_bf16.h>
#include <math.h>

#define B_ 256
#define T_ 256
#define CIN 64
#define HID 512
#define NH 8
#define HD 64
#define FFD 2048
#define OUTD 10

typedef __bf16 bf16x8 __attribute__((ext_vector_type(8)));
typedef float f32x4 __attribute__((ext_vector_type(4)));

// swizzled LDS byte offset for a [rows x 512] bf16 tile (row stride 1024B)
#define HSOFF(r,c) (((r)<<10) + ((((c)<<1)) ^ ((((r)&7))<<4)))

__device__ __forceinline__ float bf2f(unsigned u){
  union { unsigned i; float f; } c; c.i = u << 16; return c.f;
}
__device__ __forceinline__ unsigned pk2(float a, float b){
  return ((unsigned)__bfloat16_as_ushort(__float2bfloat16(a))) |
         (((unsigned)__bfloat16_as_ushort(__float2bfloat16(b))) << 16);
}

// ---------------- pack: f32 weight (N x K) -> bf16 MFMA-fragment order ----------------
__device__ __forceinline__ void pack_one(const float* __restrict__ W,
                                         __hip_bfloat16* __restrict__ P,
                                         const int K, int g){
  int row = g / (K/8), kg = g % (K/8);
  int k0 = kg*8;
  int n0 = row >> 6, j = (row >> 4) & 3, lr = row & 15;
  int s = k0 >> 5, lg = (k0 >> 3) & 3;
  int lane = lg*16 + lr;
  const float* src = W + (size_t)row*K + k0;
  float4 a = *(const float4*)src;
  float4 b = *(const float4*)(src+4);
  uint4 p = { pk2(a.x,a.y), pk2(a.z,a.w), pk2(b.x,b.y), pk2(b.z,b.w) };
  size_t off = ((((size_t)n0*(K>>5) + s)*4 + j)*64 + lane)*8;
  *(uint4*)(P + off) = p;
}

#define G_KV (HID*HID/8)   // 32768
#define G_FF (FFD*HID/8)   // 131072
#define G_IP (HID*CIN/8)   // 4096
#define G_I  (CIN*128/8)   // 1024
#define PK_TOT (4*G_KV + 2*G_FF + G_IP + G_I)
__global__ __launch_bounds__(256) void k_pack(
    const float* __restrict__ Wk, const float* __restrict__ Wv,
    const float* __restrict__ Wo, const float* __restrict__ Wq,
    const float* __restrict__ W1, const float* __restrict__ W2,
    const float* __restrict__ Wip, const float* __restrict__ Wi,
    __hip_bfloat16* __restrict__ Pk, __hip_bfloat16* __restrict__ Pv,
    __hip_bfloat16* __restrict__ Po, __hip_bfloat16* __restrict__ Pq,
    __hip_bfloat16* __restrict__ P1, __hip_bfloat16* __restrict__ P2,
    __hip_bfloat16* __restrict__ Pip, __hip_bfloat16* __restrict__ Pi)
{
  int g = blockIdx.x*256 + threadIdx.x;
  if (g < G_KV) { pack_one(Wk, Pk, HID, g); return; }  g -= G_KV;
  if (g < G_KV) { pack_one(Wv, Pv, HID, g); return; }  g -= G_KV;
  if (g < G_KV) { pack_one(Wo, Po, HID, g); return; }  g -= G_KV;
  if (g < G_KV) { pack_one(Wq, Pq, HID, g); return; }  g -= G_KV;
  if (g < G_FF) { pack_one(W1, P1, HID, g); return; }  g -= G_FF;
  if (g < G_FF) { pack_one(W2, P2, FFD, g); return; }  g -= G_FF;
  if (g < G_IP) { pack_one(Wip, Pip, CIN, g); return; }  g -= G_IP;
  if (g < G_I ) { pack_one(Wi, Pi, 128, g); }
}

// ---- building block (M=64): A(64x64 in Hs cols 0..64) @ Wip^T + LN -> Hs (64x512 bf16) ----
__device__ __forceinline__ void proj_ln(
    char* Hs, const __hip_bfloat16* __restrict__ Pip,
    const float* __restrict__ bip, const float* __restrict__ g_in,
    const float* __restrict__ b_in,
    float (*red)[8][2], float (*ms2)[2],
    int tid, int w, int l, int lr, int lg)
{
  f32x4 acc[4][4];
  #pragma unroll
  for (int i=0;i<4;i++)
    #pragma unroll
    for (int j=0;j<4;j++) acc[i][j] = (f32x4){0.f,0.f,0.f,0.f};
  #pragma unroll
  for (int s = 0; s < 2; s++){
    bf16x8 af[4], bfr[4];
    #pragma unroll
    for (int i=0;i<4;i++)
      af[i] = *(const bf16x8*)(Hs + HSOFF(i*16 + lr, s*32 + lg*8));
    const __hip_bfloat16* fb = Pip + ((size_t)(w*2 + s)*4)*512 + l*8;
    #pragma unroll
    for (int j=0;j<4;j++)
      bfr[j] = *(const bf16x8*)(fb + j*512);
    #pragma unroll
    for (int i=0;i<4;i++)
      #pragma unroll
      for (int j=0;j<4;j++)
        acc[i][j] = __builtin_amdgcn_mfma_f32_16x16x32_bf16(af[i], bfr[j], acc[i][j], 0,0,0);
  }
  float bipv[4], gv[4], bbv[4];
  #pragma unroll
  for (int j=0;j<4;j++){
    int col = w*64 + j*16 + lr;
    bipv[j] = bip[col]; gv[j] = g_in[col]; bbv[j] = b_in[col];
  }
  #pragma unroll
  for (int i=0;i<4;i++){
    #pragma unroll
    for (int r=0;r<4;r++){
      float s = 0.f, s2 = 0.f;
      #pragma unroll
      for (int j=0;j<4;j++){ float v = acc[i][j][r] + bipv[j]; s += v; s2 += v*v; }
      #pragma unroll
      for (int o=1;o<16;o<<=1){ s += __shfl_xor(s,o); s2 += __shfl_xor(s2,o); }
      if (lr == 0){ int row = i*16 + lg*4 + r; red[row][w][0] = s; red[row][w][1] = s2; }
    }
  }
  __syncthreads();
  if (tid < 64){
    float S = 0.f, S2 = 0.f;
    #pragma unroll
    for (int k=0;k<8;k++){ S += red[tid][k][0]; S2 += red[tid][k][1]; }
    float m = S*(1.f/512.f), var = S2*(1.f/512.f) - m*m;
    ms2[tid][0] = m; ms2[tid][1] = rsqrtf(var + 1e-5f);
  }
  __syncthreads();
  #pragma unroll
  for (int i=0;i<4;i++){
    #pragma unroll
    for (int r=0;r<4;r++){
      int row = i*16 + lg*4 + r;
      float m = ms2[row][0], rs = ms2[row][1];
      #pragma unroll
      for (int j=0;j<4;j++){
        int col = w*64 + j*16 + lr;
        float v = (acc[i][j][r] + bipv[j] - m)*rs*gv[j] + bbv[j];
        *(unsigned short*)(Hs + HSOFF(row, col)) =
            __bfloat16_as_ushort(__float2bfloat16(v));
      }
    }
  }
  __syncthreads();
}

// ---- building block (M=64): acc = Hs(64x512) @ P^T (K=512, packed, n0 pre-applied) ----
__device__ __forceinline__ void gemm512_pk(
    const char* Hs, const __hip_bfloat16* __restrict__ Pm,
    f32x4 acc[4][4], int l, int lr, int lg)
{
  #pragma unroll
  for (int i=0;i<4;i++)
    #pragma unroll
    for (int j=0;j<4;j++) acc[i][j] = (f32x4){0.f,0.f,0.f,0.f};
  #pragma unroll
  for (int s = 0; s < 16; s++){
    bf16x8 af[4], bfr[4];
    #pragma unroll
    for (int i=0;i<4;i++)
      af[i] = *(const bf16x8*)(Hs + HSOFF(i*16 + lr, s*32 + lg*8));
    const __hip_bfloat16* fb = Pm + (size_t)s*2048 + l*8;
    #pragma unroll
    for (int j=0;j<4;j++)
      bfr[j] = *(const bf16x8*)(fb + j*512);
    #pragma unroll
    for (int i=0;i<4;i++)
      #pragma unroll
      for (int j=0;j<4;j++)
        acc[i][j] = __builtin_amdgcn_mfma_f32_16x16x32_bf16(af[i], bfr[j], acc[i][j], 0,0,0);
  }
}

// ---- building block (M=16): A(16x64 in Hs cols 0..64) @ Wip^T + LN -> Hs (16x512 bf16) ----
__device__ __forceinline__ void proj_ln16(
    char* Hs, const __hip_bfloat16* __restrict__ Pip,
    const float* __restrict__ bip, const float* __restrict__ g_in,
    const float* __restrict__ b_in,
    float (*red)[8][2], float (*ms2)[2],
    int tid, int w, int l, int lr, int lg)
{
  f32x4 acc[4];
  #pragma unroll
  for (int j=0;j<4;j++) acc[j] = (f32x4){0.f,0.f,0.f,0.f};
  #pragma unroll
  for (int s = 0; s < 2; s++){
    bf16x8 af = *(const bf16x8*)(Hs + HSOFF(lr, s*32 + lg*8));
    const __hip_bfloat16* fb = Pip + ((size_t)(w*2 + s)*4)*512 + l*8;
    #pragma unroll
    for (int j=0;j<4;j++){
      bf16x8 bfr = *(const bf16x8*)(fb + j*512);
      acc[j] = __builtin_amdgcn_mfma_f32_16x16x32_bf16(af, bfr, acc[j], 0,0,0);
    }
  }
  float bipv[4], gv[4], bbv[4];
  #pragma unroll
  for (int j=0;j<4;j++){
    int col = w*64 + j*16 + lr;
    bipv[j] = bip[col]; gv[j] = g_in[col]; bbv[j] = b_in[col];
  }
  #pragma unroll
  for (int r=0;r<4;r++){
    float s = 0.f, s2 = 0.f;
    #pragma unroll
    for (int j=0;j<4;j++){ float v = acc[j][r] + bipv[j]; s += v; s2 += v*v; }
    #pragma unroll
    for (int o=1;o<16;o<<=1){ s += __shfl_xor(s,o); s2 += __shfl_xor(s2,o); }
    if (lr == 0){ int row = lg*4 + r; red[row][w][0] = s; red[row][w][1] = s2; }
  }
  __syncthreads();
  if (tid < 16){
    float S = 0.f, S2 = 0.f;
    #pragma unroll
    for (int k=0;k<8;k++){ S += red[tid][k][0]; S2 += red[tid][k][1]; }
    float m = S*(1.f/512.f), var = S2*(1.f/512.f) - m*m;
    ms2[tid][0] = m; ms2[tid][1] = rsqrtf(var + 1e-5f);
  }
  __syncthreads();
  #pragma unroll
  for (int r=0;r<4;r++){
    int row = lg*4 + r;
    float m = ms2[row][0], rs = ms2[row][1];
    #pragma unroll
    for (int j=0;j<4;j++){
      int col = w*64 + j*16 + lr;
      float v = (acc[j][r] + bipv[j] - m)*rs*gv[j] + bbv[j];
      *(unsigned short*)(Hs + HSOFF(row, col)) =
          __bfloat16_as_ushort(__float2bfloat16(v));
    }
  }
  __syncthreads();
}

// ---- building block (M=16): acc = Hs(16x512) @ P^T (K=512, packed, n0 pre-applied) ----
__device__ __forceinline__ void gemm512_pk16(
    const char* Hs, const __hip_bfloat16* __restrict__ Pm,
    f32x4 acc[4], int l, int lr, int lg)
{
  #pragma unroll
  for (int j=0;j<4;j++) acc[j] = (f32x4){0.f,0.f,0.f,0.f};
  #pragma unroll
  for (int s = 0; s < 16; s++){
    bf16x8 af = *(const bf16x8*)(Hs + HSOFF(lr, s*32 + lg*8));
    const __hip_bfloat16* fb = Pm + (size_t)s*2048 + l*8;
    #pragma unroll
    for (int j=0;j<4;j++){
      bf16x8 bfr = *(const bf16x8*)(fb + j*512);
      acc[j] = __builtin_amdgcn_mfma_f32_16x16x32_bf16(af, bfr, acc[j], 0,0,0);
    }
  }
}

// ---------------- k_pre: batched init path (q, yinit), 16 blocks x 16 batch rows ----------
__global__ __launch_bounds__(512) void k_pre(
    const float* __restrict__ initial, const float* __restrict__ logsig,
    const __hip_bfloat16* __restrict__ Pi,  const float* __restrict__ bi,
    const __hip_bfloat16* __restrict__ Pip, const float* __restrict__ bip,
    const float* __restrict__ g_in, const float* __restrict__ b_in,
    const __hip_bfloat16* __restrict__ Pq, const float* __restrict__ bq,
    const __hip_bfloat16* __restrict__ Pk, const float* __restrict__ bk,
    const __hip_bfloat16* __restrict__ Pv, const float* __restrict__ bv,
    float* __restrict__ qout, float* __restrict__ yinit)
{
  int b0 = blockIdx.x*16;
  int tid = threadIdx.x;
  int w = tid >> 6, l = tid & 63, lr = l & 15, lg = l >> 4;
  __shared__ __align__(16) char Hs[16*1024];
  __shared__ float red[16][8][2];
  __shared__ float ms2[16][2];
  __shared__ float salS[16][8];
  f32x4 acc[4];

  // ---- phase A: stage xlast (16 rows x 64 cols) -> Hs; hq = LN(x @ Wip^T) ----
  {
    int row = tid >> 5, c = (tid & 31)*2;
    const float* s = logsig + ((size_t)(b0+row)*T_ + (T_-1))*CIN + c;
    float2 a = *(const float2*)s;
    *(unsigned*)(Hs + HSOFF(row, c)) = pk2(a.x, a.y);
  }
  __syncthreads();
  proj_ln16(Hs, Pip, bip, g_in, b_in, red, ms2, tid, w, l, lr, lg);

  // ---- phase B: q = softmax_h(hq @ Wq_h^T + bq), kept in registers ----
  float qreg[4][4];   // [j][r]
  gemm512_pk16(Hs, Pq + (size_t)w*32768, acc, l, lr, lg);
  {
    float bqv[4];
    #pragma unroll
    for (int j=0;j<4;j++) bqv[j] = bq[w*64 + j*16 + lr];
    #pragma unroll
    for (int r=0;r<4;r++){
      float v0 = acc[0][r]+bqv[0], v1 = acc[1][r]+bqv[1];
      float v2 = acc[2][r]+bqv[2], v3 = acc[3][r]+bqv[3];
      float mx = fmaxf(fmaxf(v0,v1),fmaxf(v2,v3));
      #pragma unroll
      for (int o=1;o<16;o<<=1) mx = fmaxf(mx, __shfl_xor(mx,o));
      float e0=__expf(v0-mx), e1=__expf(v1-mx), e2=__expf(v2-mx), e3=__expf(v3-mx);
      float se = e0+e1+e2+e3;
      #pragma unroll
      for (int o=1;o<16;o<<=1) se += __shfl_xor(se,o);
      float inv = 1.f/se;
      qreg[0][r]=e0*inv; qreg[1][r]=e1*inv; qreg[2][r]=e2*inv; qreg[3][r]=e3*inv;
      int row = lg*4 + r;
      size_t base = (size_t)(b0+row)*HID + w*64 + lr;
      qout[base +  0] = qreg[0][r]; qout[base + 16] = qreg[1][r];
      qout[base + 32] = qreg[2][r]; qout[base + 48] = qreg[3][r];
    }
  }
  __syncthreads();

  // ---- phase C: stage initial (16x128) -> Hs cols 64..192; ip = initial@Wi^T+bi -> cols 0..64
  {
    int row = tid >> 5, c = (tid & 31)*4;
    const float* s = initial + (size_t)(b0+row)*128 + c;
    float4 a = *(const float4*)s;
    uint2 p = { pk2(a.x,a.y), pk2(a.z,a.w) };
    *(uint2*)(Hs + HSOFF(row, 64 + c)) = p;
  }
  __syncthreads();
  if (w < 4){
    f32x4 a2 = (f32x4){0.f,0.f,0.f,0.f};
    #pragma unroll
    for (int s = 0; s < 4; s++){
      bf16x8 af = *(const bf16x8*)(Hs + HSOFF(lr, 64 + s*32 + lg*8));
      bf16x8 bfr = *(const bf16x8*)(Pi + ((size_t)s*4 + w)*512 + l*8);
      a2 = __builtin_amdgcn_mfma_f32_16x16x32_bf16(af, bfr, a2, 0,0,0);
    }
    float bic = bi[w*16 + lr];
    #pragma unroll
    for (int r=0;r<4;r++){
      *(unsigned short*)(Hs + HSOFF(lg*4 + r, w*16 + lr)) =
          __bfloat16_as_ushort(__float2bfloat16(a2[r] + bic));
    }
  }
  __syncthreads();

  // ---- phase D: h0 = LN(ip @ Wip^T) -> Hs ----
  proj_ln16(Hs, Pip, bip, g_in, b_in, red, ms2, tid, w, l, lr, lg);

  // ---- phase E: k0 scores; sal = softmax(k0).q ----
  gemm512_pk16(Hs, Pk + (size_t)w*32768, acc, l, lr, lg);
  {
    float bkv[4];
    #pragma unroll
    for (int j=0;j<4;j++) bkv[j] = bk[w*64 + j*16 + lr];
    #pragma unroll
    for (int r=0;r<4;r++){
      float v0 = acc[0][r]+bkv[0], v1 = acc[1][r]+bkv[1];
      float v2 = acc[2][r]+bkv[2], v3 = acc[3][r]+bkv[3];
      float mx = fmaxf(fmaxf(v0,v1),fmaxf(v2,v3));
      #pragma unroll
      for (int o=1;o<16;o<<=1) mx = fmaxf(mx, __shfl_xor(mx,o));
      float e0=__expf(v0-mx), e1=__expf(v1-mx), e2=__expf(v2-mx), e3=__expf(v3-mx);
      float se = e0+e1+e2+e3;
      float sq = e0*qreg[0][r]+e1*qreg[1][r]+e2*qreg[2][r]+e3*qreg[3][r];
      #pragma unroll
      for (int o=1;o<16;o<<=1){ se += __shfl_xor(se,o); sq += __shfl_xor(sq,o); }
      if (lr == 0) salS[lg*4 + r][w] = sq/se;
    }
  }
  __syncthreads();

  // ---- phase F: v0; yinit = sal * v0 ----
  gemm512_pk16(Hs, Pv + (size_t)w*32768, acc, l, lr, lg);
  {
    float bvv[4];
    #pragma unroll
    for (int j=0;j<4;j++) bvv[j] = bv[w*64 + j*16 + lr];
    #pragma unroll
    for (int r=0;r<4;r++){
      int row = lg*4 + r;
      float s = salS[row][w];
      size_t base = (size_t)(b0+row)*HID + w*64 + lr;
      yinit[base +  0] = s*(acc[0][r]+bvv[0]);
      yinit[base + 16] = s*(acc[1][r]+bvv[1]);
      yinit[base + 32] = s*(acc[2][r]+bvv[2]);
      yinit[base + 48] = s*(acc[3][r]+bvv[3]);
    }
  }
}

// ---------------- FUSED kernel (r11 structure): hln + score + softmax.q + MFMA partial-u ---
__global__ __launch_bounds__(512, 4) void k_fused(
    const float* __restrict__ logsig,
    const __hip_bfloat16* __restrict__ Pip,
    const float* __restrict__ bip,
    const float* __restrict__ g_in, const float* __restrict__ b_in,
    const __hip_bfloat16* __restrict__ Pk,
    const float* __restrict__ bk,
    const float* __restrict__ qws,             // (B,512)
    float* __restrict__ up,                    // (B,NH,4,512) f32 partial u
    float* __restrict__ Asp)                   // (B,NH,4) partial alpha-sum
{
  int b = blockIdx.x, tc = blockIdx.y;
  int tid = threadIdx.x;
  int w = tid >> 6, l = tid & 63, lr = l & 15, lg = l >> 4;
  __shared__ __align__(16) char Hs[64*1024];     // 64 rows x 512 bf16, swizzled
  __shared__ float red[64][8][2];
  __shared__ float ms2[64][2];
  __shared__ float als[64][8];
  __shared__ unsigned short als_bt[2][16][64];   // alpha^T bf16 hi/lo (rows 8-15 unused)

  // ---- stage logsig x-tile (64x64 f32 -> bf16) into Hs cols 0..64 ----
  {
    int row = tid >> 3, cc = (tid & 7)*8;
    const float* srow = logsig + ((size_t)b*T_ + tc*64 + row)*CIN + cc;
    float4 a = *(const float4*)(srow);
    float4 c = *(const float4*)(srow+4);
    uint4 p = { pk2(a.x,a.y), pk2(a.z,a.w), pk2(c.x,c.y), pk2(c.z,c.w) };
    *(uint4*)(Hs + HSOFF(row, cc)) = p;
  }
  __syncthreads();

  // ---- phase 1: Hln = LN(x @ Wip^T + bip) ----
  proj_ln(Hs, Pip, bip, g_in, b_in, red, ms2, tid, w, l, lr, lg);

  // ---- phase 2: scores S = Hln @ Wk_h^T (wave w = head w), A from LDS ----
  f32x4 acc[4][4];
  gemm512_pk(Hs, Pk + (size_t)w*32768, acc, l, lr, lg);

  // ---- phase 3: per-row softmax over head cols, dot q, RK4 weight -> als (+bf16 hi/lo T) ----
  {
    float bkv[4], qv[4];
    #pragma unroll
    for (int j=0;j<4;j++){
      bkv[j] = bk[w*64 + j*16 + lr];
      qv[j]  = qws[(size_t)b*HID + w*64 + j*16 + lr];
    }
    #pragma unroll
    for (int i=0;i<4;i++){
      #pragma unroll
      for (int r=0;r<4;r++){
        float v0 = acc[i][0][r]+bkv[0], v1 = acc[i][1][r]+bkv[1];
        float v2 = acc[i][2][r]+bkv[2], v3 = acc[i][3][r]+bkv[3];
        float mx = fmaxf(fmaxf(v0,v1),fmaxf(v2,v3));
        #pragma unroll
        for (int o=1;o<16;o<<=1) mx = fmaxf(mx, __shfl_xor(mx,o));
        float e0=__expf(v0-mx), e1=__expf(v1-mx), e2=__expf(v2-mx), e3=__expf(v3-mx);
        float se = e0+e1+e2+e3;
        float sq = e0*qv[0]+e1*qv[1]+e2*qv[2]+e3*qv[3];
        #pragma unroll
        for (int o=1;o<16;o<<=1){ se += __shfl_xor(se,o); sq += __shfl_xor(sq,o); }
        if (lr == 0){
          int row = i*16 + lg*4 + r;
          int t = tc*64 + row;
          float wt = (t == 0) ? (5.f/6.f) : ((t == T_-1) ? (1.f/6.f) : 1.f);
          float alpha = wt * sq / se;
          als[row][w] = alpha;
          __hip_bfloat16 ah = __float2bfloat16(alpha);
          float rem = alpha - __bfloat162float(ah);
          als_bt[0][w][row] = __bfloat16_as_ushort(ah);
          als_bt[1][w][row] = __bfloat16_as_ushort(__float2bfloat16(rem));
        }
      }
    }
  }
  __syncthreads();

  // ---- phase 4: u = alpha^T @ H via MFMA (M=8 heads, N=64 cols/wave, K=64 rows) ----
  {
    f32x4 uacc[4];
    #pragma unroll
    for (int t=0;t<4;t++) uacc[t] = (f32x4){0.f,0.f,0.f,0.f};
    #pragma unroll
    for (int ks=0; ks<2; ks++){
      bf16x8 afh = *(const bf16x8*)&als_bt[0][lr][ks*32 + lg*8];
      bf16x8 afl = *(const bf16x8*)&als_bt[1][lr][ks*32 + lg*8];
      #pragma unroll
      for (int t=0;t<4;t++){
        int col = w*64 + t*16 + lr;
        int r0 = ks*32 + lg*8;
        uint4 bbu;
        {
          unsigned lo0 = *(const unsigned short*)(Hs + HSOFF(r0,   col));
          unsigned hi0 = *(const unsigned short*)(Hs + HSOFF(r0+1, col));
          unsigned lo1 = *(const unsigned short*)(Hs + HSOFF(r0+2, col));
          unsigned hi1 = *(const unsigned short*)(Hs + HSOFF(r0+3, col));
          unsigned lo2 = *(const unsigned short*)(Hs + HSOFF(r0+4, col));
          unsigned hi2 = *(const unsigned short*)(Hs + HSOFF(r0+5, col));
          unsigned lo3 = *(const unsigned short*)(Hs + HSOFF(r0+6, col));
          unsigned hi3 = *(const unsigned short*)(Hs + HSOFF(r0+7, col));
          bbu.x = lo0 | (hi0 << 16);
          bbu.y = lo1 | (hi1 << 16);
          bbu.z = lo2 | (hi2 << 16);
          bbu.w = lo3 | (hi3 << 16);
        }
        bf16x8 bvv = __builtin_bit_cast(bf16x8, bbu);
        uacc[t] = __builtin_amdgcn_mfma_f32_16x16x32_bf16(afh, bvv, uacc[t], 0,0,0);
        uacc[t] = __builtin_amdgcn_mfma_f32_16x16x32_bf16(afl, bvv, uacc[t], 0,0,0);
      }
    }
    if (lg < 2){
      #pragma unroll
      for (int t=0;t<4;t++){
        #pragma unroll
        for (int rr=0; rr<4; rr++){
          int h = lg*4 + rr;
          up[((((size_t)b*NH + h)*4 + tc)*HID) + w*64 + t*16 + lr] = uacc[t][rr];
        }
      }
    }
    float s = als[l][w];
    #pragma unroll
    for (int o=1;o<64;o<<=1) s += __shfl_xor(s,o);
    if (l == 0) Asp[(((size_t)b*NH + w)*4) + tc] = s;
  }
}

// ---------------- reduce partials: u_bf (bf16) and Asum ----------------
__global__ __launch_bounds__(256) void k_ured(
    const float* __restrict__ up, const float* __restrict__ Asp,
    __hip_bfloat16* __restrict__ u_bf, float* __restrict__ Asum)
{
  int bh = blockIdx.x, tid = threadIdx.x;
  size_t base = (size_t)bh*4*HID;
  float s0 = 0.f, s1 = 0.f;
  #pragma unroll
  for (int c=0;c<4;c++){
    s0 += up[base + (size_t)c*HID + 2*tid];
    s1 += up[base + (size_t)c*HID + 2*tid+1];
  }
  ((unsigned*)u_bf)[(size_t)bh*(HID/2) + tid] = pk2(s0, s1);
  if (tid == 0)
    Asum[bh] = Asp[(size_t)bh*4] + Asp[(size_t)bh*4+1] + Asp[(size_t)bh*4+2] + Asp[(size_t)bh*4+3];
}

// ---------------- k_tail_a: yh + Wo + LN (dup x4) + quarter FF1 + partial FF2 --------------
// Grid (16, 4): blockIdx.x = 16-row group, blockIdx.y = FF quarter qd.
__global__ __launch_bounds__(512) void k_tail_a(
    const __hip_bfloat16* __restrict__ u_bf,   // (B,8,512)
    const __hip_bfloat16* __restrict__ Pv,
    const float* __restrict__ bv, const float* __restrict__ Asum,
    const float* __restrict__ yinit,
    const __hip_bfloat16* __restrict__ Po, const float* __restrict__ bo,
    const float* __restrict__ g_ff, const float* __restrict__ b_ff,
    const __hip_bfloat16* __restrict__ P1, const float* __restrict__ b1,
    const __hip_bfloat16* __restrict__ P2,
    float* __restrict__ yo,                    // (B,512) f32 (written by qd==0)
    float* __restrict__ yp2)                   // (16,4,16,512) f32 partial y2
{
  int b0 = blockIdx.x*16;
  int qd = blockIdx.y;
  int tid = threadIdx.x;
  int w = tid >> 6, l = tid & 63, lr = l & 15, lg = l >> 4;
  __shared__ __align__(16) char Hs[16*1024];     // 16x512 bf16 swizzled (yh, then yln)
  __shared__ __align__(16) char A1q[16*1024];    // 16x512 bf16 swizzled (ff1 quarter)
  __shared__ float red[16][8][2];
  __shared__ float ms2[16][2];
  f32x4 acc[4];

  // ---- phase 1: yh = u @ Wv_h^T + yinit + bv*Asum -> Hs ----
  #pragma unroll
  for (int j=0;j<4;j++) acc[j] = (f32x4){0.f,0.f,0.f,0.f};
  #pragma unroll
  for (int s = 0; s < 16; s++){
    bf16x8 af = *(const bf16x8*)(u_bf + ((size_t)(b0 + lr)*NH + w)*HID + s*32 + lg*8);
    const __hip_bfloat16* fb = Pv + (size_t)w*32768 + (size_t)s*2048 + l*8;
    #pragma unroll
    for (int j=0;j<4;j++){
      bf16x8 bfr = *(const bf16x8*)(fb + j*512);
      acc[j] = __builtin_amdgcn_mfma_f32_16x16x32_bf16(af, bfr, acc[j], 0,0,0);
    }
  }
  {
    float bvv[4];
    #pragma unroll
    for (int j=0;j<4;j++) bvv[j] = bv[w*64 + j*16 + lr];
    #pragma unroll
    for (int r=0;r<4;r++){
      int row = lg*4 + r;
      float As = Asum[(size_t)(b0+row)*NH + w];
      #pragma unroll
      for (int j=0;j<4;j++){
        int col = w*64 + j*16 + lr;
        float v = acc[j][r] + yinit[(size_t)(b0+row)*HID + col] + bvv[j]*As;
        *(unsigned short*)(Hs + HSOFF(row, col)) =
            __bfloat16_as_ushort(__float2bfloat16(v));
      }
    }
  }
  __syncthreads();

  // ---- phase 2: yo = yh @ Wo^T + bo (regs); LN -> yln overwrites Hs; qd==0 writes yo ----
  gemm512_pk16(Hs, Po + (size_t)w*32768, acc, l, lr, lg);
  {
    float bov[4], gv[4], bbv[4];
    #pragma unroll
    for (int j=0;j<4;j++){
      int col = w*64 + j*16 + lr;
      bov[j] = bo[col]; gv[j] = g_ff[col]; bbv[j] = b_ff[col];
    }
    #pragma unroll
    for (int r=0;r<4;r++){
      int row = lg*4 + r;
      float s = 0.f, s2 = 0.f;
      #pragma unroll
      for (int j=0;j<4;j++){
        float v = acc[j][r] + bov[j];
        s += v; s2 += v*v;
      }
      #pragma unroll
      for (int o=1;o<16;o<<=1){ s += __shfl_xor(s,o); s2 += __shfl_xor(s2,o); }
      if (lr == 0){ red[row][w][0] = s; red[row][w][1] = s2; }
    }
    __syncthreads();
    if (tid < 16){
      float S = 0.f, S2 = 0.f;
      #pragma unroll
      for (int k=0;k<8;k++){ S += red[tid][k][0]; S2 += red[tid][k][1]; }
      float m = S*(1.f/512.f), var = S2*(1.f/512.f) - m*m;
      ms2[tid][0] = m; ms2[tid][1] = rsqrtf(var + 1e-5f);
    }
    __syncthreads();
    #pragma unroll
    for (int r=0;r<4;r++){
      int row = lg*4 + r;
      float m = ms2[row][0], rs = ms2[row][1];
      #pragma unroll
      for (int j=0;j<4;j++){
        int col = w*64 + j*16 + lr;
        float v = acc[j][r] + bov[j];
        if (qd == 0) yo[(size_t)(b0+row)*HID + col] = v;
        *(unsigned short*)(Hs + HSOFF(row, col)) =
            __bfloat16_as_ushort(__float2bfloat16((v - m)*rs*gv[j] + bbv[j]));
      }
    }
  }
  __syncthreads();

  // ---- phase 3': a1 quarter qd: wave w -> W1 tile (qd*8+w); cols local w*64.. ----
  gemm512_pk16(Hs, P1 + (size_t)(qd*8 + w)*32768, acc, l, lr, lg);
  {
    #pragma unroll
    for (int j=0;j<4;j++){
      int lcol = w*64 + j*16 + lr;
      float bc = b1[(qd*8 + w)*64 + j*16 + lr];
      #pragma unroll
      for (int r=0;r<4;r++){
        int row = lg*4 + r;
        *(unsigned short*)(A1q + HSOFF(row, lcol)) =
            __bfloat16_as_ushort(__float2bfloat16(fmaxf(acc[j][r] + bc, 0.f)));
      }
    }
  }
  __syncthreads();

  // ---- phase 4': partial y2 = a1q @ W2[:, qd-quarter]^T -> yp2 ----
  {
    const __hip_bfloat16* Pm = P2 + ((size_t)(w*64 + qd*16)*4)*512;
    gemm512_pk16(A1q, Pm, acc, l, lr, lg);
    #pragma unroll
    for (int r=0;r<4;r++){
      int row = lg*4 + r;
      #pragma unroll
      for (int j=0;j<4;j++){
        int col = w*64 + j*16 + lr;
        yp2[((((size_t)blockIdx.x*4 + qd)*16) + row)*HID + col] = acc[j][r];
      }
    }
  }
}

// ---------------- k_fin: y2 = yo + b2 + sum(partials); out = y2 @ Wf^T + bf ----------------
__global__ __launch_bounds__(512) void k_fin(
    const float* __restrict__ yo, const float* __restrict__ yp2,
    const float* __restrict__ b2,
    const float* __restrict__ Wf, const float* __restrict__ bfv,
    float* __restrict__ out)
{
  int g = blockIdx.x, b0 = g*16;
  int tid = threadIdx.x;
  __shared__ float yoS[16][516];
  for (int i = tid; i < 16*HID; i += 512){
    int row = i >> 9, col = i & 511;
    size_t pb = (((size_t)g*4)*16 + row)*HID + col;
    float v = yo[(size_t)(b0+row)*HID + col] + b2[col]
            + yp2[pb] + yp2[pb + 16*HID] + yp2[pb + 2*16*HID] + yp2[pb + 3*16*HID];
    yoS[row][col] = v;
  }
  __syncthreads();
  {
    int pair = tid >> 1, half = tid & 1;
    if (pair < 16*OUTD){
      int row = pair / OUTD, oc = pair % OUTD;
      const float4* wr = (const float4*)(Wf + (size_t)oc*HID) + half*64;
      float sacc = 0.f;
      #pragma unroll 8
      for (int k4 = 0; k4 < 64; k4++){
        float4 a = wr[k4];
        int c = half*256 + k4*4;
        sacc += a.x*yoS[row][c] + a.y*yoS[row][c+1]
              + a.z*yoS[row][c+2] + a.w*yoS[row][c+3];
      }
      sacc += __shfl_xor(sacc, 1);
      if (half == 0) out[(size_t)(b0+row)*OUTD + oc] = bfv[oc] + sacc;
    }
  }
}

extern "C" void kernel_launch(void* const* d_in, const int* in_sizes, int n_in,
                              void* d_out, int out_size, void* d_ws, size_t ws_size,
                              hipStream_t stream)
{
  const float* initial = (const float*)d_in[0];
  const float* logsig  = (const float*)d_in[1];
  const float* Wi  = (const float*)d_in[2];  const float* bi  = (const float*)d_in[3];
  const float* Wip = (const float*)d_in[4];  const float* bip = (const float*)d_in[5];
  const float* g_in= (const float*)d_in[6];  const float* b_in= (const float*)d_in[7];
  const float* Wk  = (const float*)d_in[8];  const float* bk  = (const float*)d_in[9];
  const float* Wv  = (const float*)d_in[10]; const float* bv  = (const float*)d_in[11];
  const float* Wq  = (const float*)d_in[12]; const float* bq  = (const float*)d_in[13];
  const float* Wo  = (const float*)d_in[14]; const float* bo  = (const float*)d_in[15];
  const float* g_ff= (const float*)d_in[16]; const float* b_ff= (const float*)d_in[17];
  const float* W1  = (const float*)d_in[18]; const float* b1  = (const float*)d_in[19];
  const float* W2  = (const float*)d_in[20]; const float* b2  = (const float*)d_in[21];
  const float* Wf  = (const float*)d_in[22]; const float* bf  = (const float*)d_in[23];
  float* out = (float*)d_out;

  char* ws = (char*)d_ws;
  const size_t MB = 1<<20;
  float* qws   = (float*)(ws);                             // 512 KB
  float* yinit = (float*)(ws + 512*1024);                  // 512 KB
  __hip_bfloat16* u_bf = (__hip_bfloat16*)(ws + 3*MB);     // 2 MB
  float* Asum  = (float*)(ws + 5*MB);                      // 8 KB
  __hip_bfloat16* Pk  = (__hip_bfloat16*)(ws + 5*MB + 512*1024);  // 512 KB
  __hip_bfloat16* Pv  = (__hip_bfloat16*)(ws + 6*MB);      // 512 KB
  __hip_bfloat16* P1  = (__hip_bfloat16*)(ws + 6*MB + 512*1024);  // 2 MB
  __hip_bfloat16* P2  = (__hip_bfloat16*)(ws + 8*MB + 512*1024);  // 2 MB
  float* yo    = (float*)(ws + 10*MB + 512*1024);          // 512 KB
  __hip_bfloat16* Po  = (__hip_bfloat16*)(ws + 13*MB);     // 512 KB
  __hip_bfloat16* Pip = (__hip_bfloat16*)(ws + 15*MB);     // 64 KB
  float* up    = (float*)(ws + 16*MB);                     // 16 MB
  float* Asp   = (float*)(ws + 33*MB);                     // 32 KB
  __hip_bfloat16* Pq  = (__hip_bfloat16*)(ws + 34*MB);     // 512 KB
  __hip_bfloat16* Pi  = (__hip_bfloat16*)(ws + 35*MB);     // 16 KB
  float* yp2   = (float*)(ws + 36*MB);                     // 2 MB

  k_pack<<<dim3((PK_TOT + 255)/256), 256, 0, stream>>>(
      Wk, Wv, Wo, Wq, W1, W2, Wip, Wi,
      Pk, Pv, Po, Pq, P1, P2, Pip, Pi);
  k_pre<<<dim3(B_/16), 512, 0, stream>>>(initial, logsig, Pi, bi, Pip, bip,
                                         g_in, b_in, Pq, bq, Pk, bk, Pv, bv,
                                         qws, yinit);
  k_fused<<<dim3(B_, 4), 512, 0, stream>>>(logsig, Pip, bip, g_in, b_in,
                                           Pk, bk, qws, up, Asp);
  k_ured<<<dim3(B_*NH), 256, 0, stream>>>(up, Asp, u_bf, Asum);
  k_tail_a<<<dim3(B_/16, 4), 512, 0, stream>>>(u_bf, Pv, bv, Asum, yinit,
                                               Po, bo, g_ff, b_ff,
                                               P1, b1, P2, yo, yp2);
  k_fin<<<dim3(B_/16), 512, 0, stream>>>(yo, yp2, b2, Wf, bf, out);
}

// Round 20
// 159.923 us; speedup vs baseline: 3.0078x; 1.0024x over previous
//
#include <hip/hip_runtime.h>
#include <hip/hip_bf16.h>
#include <math.h>

#define B_ 256
#define T_ 256
#define CIN 64
#define HID 512
#define NH 8
#define HD 64
#define FFD 2048
#define OUTD 10

typedef __bf16 bf16x8 __attribute__((ext_vector_type(8)));
typedef float f32x4 __attribute__((ext_vector_type(4)));

// swizzled LDS byte offset for a [rows x 512] bf16 tile (row stride 1024B)
#define HSOFF(r,c) (((r)<<10) + ((((c)<<1)) ^ ((((r)&7))<<4)))
// swizzled LDS byte offset for a [rows x 2048] bf16 tile (row stride 4096B)
#define HS2OFF(r,c) (((r)<<12) + ((((c)<<1)) ^ ((((r)&7))<<4)))

__device__ __forceinline__ float bf2f(unsigned u){
  union { unsigned i; float f; } c; c.i = u << 16; return c.f;
}
__device__ __forceinline__ unsigned pk2(float a, float b){
  return ((unsigned)__bfloat16_as_ushort(__float2bfloat16(a))) |
         (((unsigned)__bfloat16_as_ushort(__float2bfloat16(b))) << 16);
}

// ---------------- pack: f32 weight (N x K) -> bf16 MFMA-fragment order ----------------
__device__ __forceinline__ void pack_one(const float* __restrict__ W,
                                         __hip_bfloat16* __restrict__ P,
                                         const int K, int g){
  int row = g / (K/8), kg = g % (K/8);
  int k0 = kg*8;
  int n0 = row >> 6, j = (row >> 4) & 3, lr = row & 15;
  int s = k0 >> 5, lg = (k0 >> 3) & 3;
  int lane = lg*16 + lr;
  const float* src = W + (size_t)row*K + k0;
  float4 a = *(const float4*)src;
  float4 b = *(const float4*)(src+4);
  uint4 p = { pk2(a.x,a.y), pk2(a.z,a.w), pk2(b.x,b.y), pk2(b.z,b.w) };
  size_t off = ((((size_t)n0*(K>>5) + s)*4 + j)*64 + lane)*8;
  *(uint4*)(P + off) = p;
}

#define G_KV (HID*HID/8)   // 32768
#define G_FF (FFD*HID/8)   // 131072
#define G_IP (HID*CIN/8)   // 4096
#define G_I  (CIN*128/8)   // 1024
#define PK_TOT (4*G_KV + 2*G_FF + G_IP + G_I)
__global__ __launch_bounds__(256) void k_pack(
    const float* __restrict__ Wk, const float* __restrict__ Wv,
    const float* __restrict__ Wo, const float* __restrict__ Wq,
    const float* __restrict__ W1, const float* __restrict__ W2,
    const float* __restrict__ Wip, const float* __restrict__ Wi,
    __hip_bfloat16* __restrict__ Pk, __hip_bfloat16* __restrict__ Pv,
    __hip_bfloat16* __restrict__ Po, __hip_bfloat16* __restrict__ Pq,
    __hip_bfloat16* __restrict__ P1, __hip_bfloat16* __restrict__ P2,
    __hip_bfloat16* __restrict__ Pip, __hip_bfloat16* __restrict__ Pi)
{
  int g = blockIdx.x*256 + threadIdx.x;
  if (g < G_KV) { pack_one(Wk, Pk, HID, g); return; }  g -= G_KV;
  if (g < G_KV) { pack_one(Wv, Pv, HID, g); return; }  g -= G_KV;
  if (g < G_KV) { pack_one(Wo, Po, HID, g); return; }  g -= G_KV;
  if (g < G_KV) { pack_one(Wq, Pq, HID, g); return; }  g -= G_KV;
  if (g < G_FF) { pack_one(W1, P1, HID, g); return; }  g -= G_FF;
  if (g < G_FF) { pack_one(W2, P2, FFD, g); return; }  g -= G_FF;
  if (g < G_IP) { pack_one(Wip, Pip, CIN, g); return; }  g -= G_IP;
  if (g < G_I ) { pack_one(Wi, Pi, 128, g); }
}

// ---- building block (M=64): A(64x64 in Hs cols 0..64) @ Wip^T + LN -> Hs (64x512 bf16) ----
__device__ __forceinline__ void proj_ln(
    char* Hs, const __hip_bfloat16* __restrict__ Pip,
    const float* __restrict__ bip, const float* __restrict__ g_in,
    const float* __restrict__ b_in,
    float (*red)[8][2], float (*ms2)[2],
    int tid, int w, int l, int lr, int lg)
{
  f32x4 acc[4][4];
  #pragma unroll
  for (int i=0;i<4;i++)
    #pragma unroll
    for (int j=0;j<4;j++) acc[i][j] = (f32x4){0.f,0.f,0.f,0.f};
  #pragma unroll
  for (int s = 0; s < 2; s++){
    bf16x8 af[4], bfr[4];
    #pragma unroll
    for (int i=0;i<4;i++)
      af[i] = *(const bf16x8*)(Hs + HSOFF(i*16 + lr, s*32 + lg*8));
    const __hip_bfloat16* fb = Pip + ((size_t)(w*2 + s)*4)*512 + l*8;
    #pragma unroll
    for (int j=0;j<4;j++)
      bfr[j] = *(const bf16x8*)(fb + j*512);
    #pragma unroll
    for (int i=0;i<4;i++)
      #pragma unroll
      for (int j=0;j<4;j++)
        acc[i][j] = __builtin_amdgcn_mfma_f32_16x16x32_bf16(af[i], bfr[j], acc[i][j], 0,0,0);
  }
  float bipv[4], gv[4], bbv[4];
  #pragma unroll
  for (int j=0;j<4;j++){
    int col = w*64 + j*16 + lr;
    bipv[j] = bip[col]; gv[j] = g_in[col]; bbv[j] = b_in[col];
  }
  #pragma unroll
  for (int i=0;i<4;i++){
    #pragma unroll
    for (int r=0;r<4;r++){
      float s = 0.f, s2 = 0.f;
      #pragma unroll
      for (int j=0;j<4;j++){ float v = acc[i][j][r] + bipv[j]; s += v; s2 += v*v; }
      #pragma unroll
      for (int o=1;o<16;o<<=1){ s += __shfl_xor(s,o); s2 += __shfl_xor(s2,o); }
      if (lr == 0){ int row = i*16 + lg*4 + r; red[row][w][0] = s; red[row][w][1] = s2; }
    }
  }
  __syncthreads();
  if (tid < 64){
    float S = 0.f, S2 = 0.f;
    #pragma unroll
    for (int k=0;k<8;k++){ S += red[tid][k][0]; S2 += red[tid][k][1]; }
    float m = S*(1.f/512.f), var = S2*(1.f/512.f) - m*m;
    ms2[tid][0] = m; ms2[tid][1] = rsqrtf(var + 1e-5f);
  }
  __syncthreads();
  #pragma unroll
  for (int i=0;i<4;i++){
    #pragma unroll
    for (int r=0;r<4;r++){
      int row = i*16 + lg*4 + r;
      float m = ms2[row][0], rs = ms2[row][1];
      #pragma unroll
      for (int j=0;j<4;j++){
        int col = w*64 + j*16 + lr;
        float v = (acc[i][j][r] + bipv[j] - m)*rs*gv[j] + bbv[j];
        *(unsigned short*)(Hs + HSOFF(row, col)) =
            __bfloat16_as_ushort(__float2bfloat16(v));
      }
    }
  }
  __syncthreads();
}

// ---- building block (M=64): acc = Hs(64x512) @ P^T (K=512, packed, n0 pre-applied) ----
__device__ __forceinline__ void gemm512_pk(
    const char* Hs, const __hip_bfloat16* __restrict__ Pm,
    f32x4 acc[4][4], int l, int lr, int lg)
{
  #pragma unroll
  for (int i=0;i<4;i++)
    #pragma unroll
    for (int j=0;j<4;j++) acc[i][j] = (f32x4){0.f,0.f,0.f,0.f};
  #pragma unroll
  for (int s = 0; s < 16; s++){
    bf16x8 af[4], bfr[4];
    #pragma unroll
    for (int i=0;i<4;i++)
      af[i] = *(const bf16x8*)(Hs + HSOFF(i*16 + lr, s*32 + lg*8));
    const __hip_bfloat16* fb = Pm + (size_t)s*2048 + l*8;
    #pragma unroll
    for (int j=0;j<4;j++)
      bfr[j] = *(const bf16x8*)(fb + j*512);
    #pragma unroll
    for (int i=0;i<4;i++)
      #pragma unroll
      for (int j=0;j<4;j++)
        acc[i][j] = __builtin_amdgcn_mfma_f32_16x16x32_bf16(af[i], bfr[j], acc[i][j], 0,0,0);
  }
}

// ---- building block (M=16): A(16x64 in Hs cols 0..64) @ Wip^T + LN -> Hs (16x512 bf16) ----
__device__ __forceinline__ void proj_ln16(
    char* Hs, const __hip_bfloat16* __restrict__ Pip,
    const float* __restrict__ bip, const float* __restrict__ g_in,
    const float* __restrict__ b_in,
    float (*red)[8][2], float (*ms2)[2],
    int tid, int w, int l, int lr, int lg)
{
  f32x4 acc[4];
  #pragma unroll
  for (int j=0;j<4;j++) acc[j] = (f32x4){0.f,0.f,0.f,0.f};
  #pragma unroll
  for (int s = 0; s < 2; s++){
    bf16x8 af = *(const bf16x8*)(Hs + HSOFF(lr, s*32 + lg*8));
    const __hip_bfloat16* fb = Pip + ((size_t)(w*2 + s)*4)*512 + l*8;
    #pragma unroll
    for (int j=0;j<4;j++){
      bf16x8 bfr = *(const bf16x8*)(fb + j*512);
      acc[j] = __builtin_amdgcn_mfma_f32_16x16x32_bf16(af, bfr, acc[j], 0,0,0);
    }
  }
  float bipv[4], gv[4], bbv[4];
  #pragma unroll
  for (int j=0;j<4;j++){
    int col = w*64 + j*16 + lr;
    bipv[j] = bip[col]; gv[j] = g_in[col]; bbv[j] = b_in[col];
  }
  #pragma unroll
  for (int r=0;r<4;r++){
    float s = 0.f, s2 = 0.f;
    #pragma unroll
    for (int j=0;j<4;j++){ float v = acc[j][r] + bipv[j]; s += v; s2 += v*v; }
    #pragma unroll
    for (int o=1;o<16;o<<=1){ s += __shfl_xor(s,o); s2 += __shfl_xor(s2,o); }
    if (lr == 0){ int row = lg*4 + r; red[row][w][0] = s; red[row][w][1] = s2; }
  }
  __syncthreads();
  if (tid < 16){
    float S = 0.f, S2 = 0.f;
    #pragma unroll
    for (int k=0;k<8;k++){ S += red[tid][k][0]; S2 += red[tid][k][1]; }
    float m = S*(1.f/512.f), var = S2*(1.f/512.f) - m*m;
    ms2[tid][0] = m; ms2[tid][1] = rsqrtf(var + 1e-5f);
  }
  __syncthreads();
  #pragma unroll
  for (int r=0;r<4;r++){
    int row = lg*4 + r;
    float m = ms2[row][0], rs = ms2[row][1];
    #pragma unroll
    for (int j=0;j<4;j++){
      int col = w*64 + j*16 + lr;
      float v = (acc[j][r] + bipv[j] - m)*rs*gv[j] + bbv[j];
      *(unsigned short*)(Hs + HSOFF(row, col)) =
          __bfloat16_as_ushort(__float2bfloat16(v));
    }
  }
  __syncthreads();
}

// ---- building block (M=16): acc = Hs(16x512) @ P^T (K=512, packed, n0 pre-applied) ----
__device__ __forceinline__ void gemm512_pk16(
    const char* Hs, const __hip_bfloat16* __restrict__ Pm,
    f32x4 acc[4], int l, int lr, int lg)
{
  #pragma unroll
  for (int j=0;j<4;j++) acc[j] = (f32x4){0.f,0.f,0.f,0.f};
  #pragma unroll
  for (int s = 0; s < 16; s++){
    bf16x8 af = *(const bf16x8*)(Hs + HSOFF(lr, s*32 + lg*8));
    const __hip_bfloat16* fb = Pm + (size_t)s*2048 + l*8;
    #pragma unroll
    for (int j=0;j<4;j++){
      bf16x8 bfr = *(const bf16x8*)(fb + j*512);
      acc[j] = __builtin_amdgcn_mfma_f32_16x16x32_bf16(af, bfr, acc[j], 0,0,0);
    }
  }
}

// ---------------- k_pre: batched init path (q, yinit), 16 blocks x 16 batch rows ----------
__global__ __launch_bounds__(512) void k_pre(
    const float* __restrict__ initial, const float* __restrict__ logsig,
    const __hip_bfloat16* __restrict__ Pi,  const float* __restrict__ bi,
    const __hip_bfloat16* __restrict__ Pip, const float* __restrict__ bip,
    const float* __restrict__ g_in, const float* __restrict__ b_in,
    const __hip_bfloat16* __restrict__ Pq, const float* __restrict__ bq,
    const __hip_bfloat16* __restrict__ Pk, const float* __restrict__ bk,
    const __hip_bfloat16* __restrict__ Pv, const float* __restrict__ bv,
    float* __restrict__ qout, float* __restrict__ yinit)
{
  int b0 = blockIdx.x*16;
  int tid = threadIdx.x;
  int w = tid >> 6, l = tid & 63, lr = l & 15, lg = l >> 4;
  __shared__ __align__(16) char Hs[16*1024];
  __shared__ float red[16][8][2];
  __shared__ float ms2[16][2];
  __shared__ float salS[16][8];
  f32x4 acc[4];

  // ---- phase A: stage xlast (16 rows x 64 cols) -> Hs; hq = LN(x @ Wip^T) ----
  {
    int row = tid >> 5, c = (tid & 31)*2;
    const float* s = logsig + ((size_t)(b0+row)*T_ + (T_-1))*CIN + c;
    float2 a = *(const float2*)s;
    *(unsigned*)(Hs + HSOFF(row, c)) = pk2(a.x, a.y);
  }
  __syncthreads();
  proj_ln16(Hs, Pip, bip, g_in, b_in, red, ms2, tid, w, l, lr, lg);

  // ---- phase B: q = softmax_h(hq @ Wq_h^T + bq), kept in registers ----
  float qreg[4][4];   // [j][r]
  gemm512_pk16(Hs, Pq + (size_t)w*32768, acc, l, lr, lg);
  {
    float bqv[4];
    #pragma unroll
    for (int j=0;j<4;j++) bqv[j] = bq[w*64 + j*16 + lr];
    #pragma unroll
    for (int r=0;r<4;r++){
      float v0 = acc[0][r]+bqv[0], v1 = acc[1][r]+bqv[1];
      float v2 = acc[2][r]+bqv[2], v3 = acc[3][r]+bqv[3];
      float mx = fmaxf(fmaxf(v0,v1),fmaxf(v2,v3));
      #pragma unroll
      for (int o=1;o<16;o<<=1) mx = fmaxf(mx, __shfl_xor(mx,o));
      float e0=__expf(v0-mx), e1=__expf(v1-mx), e2=__expf(v2-mx), e3=__expf(v3-mx);
      float se = e0+e1+e2+e3;
      #pragma unroll
      for (int o=1;o<16;o<<=1) se += __shfl_xor(se,o);
      float inv = 1.f/se;
      qreg[0][r]=e0*inv; qreg[1][r]=e1*inv; qreg[2][r]=e2*inv; qreg[3][r]=e3*inv;
      int row = lg*4 + r;
      size_t base = (size_t)(b0+row)*HID + w*64 + lr;
      qout[base +  0] = qreg[0][r]; qout[base + 16] = qreg[1][r];
      qout[base + 32] = qreg[2][r]; qout[base + 48] = qreg[3][r];
    }
  }
  __syncthreads();

  // ---- phase C: stage initial (16x128) -> Hs cols 64..192; ip = initial@Wi^T+bi -> cols 0..64
  {
    int row = tid >> 5, c = (tid & 31)*4;
    const float* s = initial + (size_t)(b0+row)*128 + c;
    float4 a = *(const float4*)s;
    uint2 p = { pk2(a.x,a.y), pk2(a.z,a.w) };
    *(uint2*)(Hs + HSOFF(row, 64 + c)) = p;
  }
  __syncthreads();
  if (w < 4){
    f32x4 a2 = (f32x4){0.f,0.f,0.f,0.f};
    #pragma unroll
    for (int s = 0; s < 4; s++){
      bf16x8 af = *(const bf16x8*)(Hs + HSOFF(lr, 64 + s*32 + lg*8));
      bf16x8 bfr = *(const bf16x8*)(Pi + ((size_t)s*4 + w)*512 + l*8);
      a2 = __builtin_amdgcn_mfma_f32_16x16x32_bf16(af, bfr, a2, 0,0,0);
    }
    float bic = bi[w*16 + lr];
    #pragma unroll
    for (int r=0;r<4;r++){
      *(unsigned short*)(Hs + HSOFF(lg*4 + r, w*16 + lr)) =
          __bfloat16_as_ushort(__float2bfloat16(a2[r] + bic));
    }
  }
  __syncthreads();

  // ---- phase D: h0 = LN(ip @ Wip^T) -> Hs ----
  proj_ln16(Hs, Pip, bip, g_in, b_in, red, ms2, tid, w, l, lr, lg);

  // ---- phase E: k0 scores; sal = softmax(k0).q ----
  gemm512_pk16(Hs, Pk + (size_t)w*32768, acc, l, lr, lg);
  {
    float bkv[4];
    #pragma unroll
    for (int j=0;j<4;j++) bkv[j] = bk[w*64 + j*16 + lr];
    #pragma unroll
    for (int r=0;r<4;r++){
      float v0 = acc[0][r]+bkv[0], v1 = acc[1][r]+bkv[1];
      float v2 = acc[2][r]+bkv[2], v3 = acc[3][r]+bkv[3];
      float mx = fmaxf(fmaxf(v0,v1),fmaxf(v2,v3));
      #pragma unroll
      for (int o=1;o<16;o<<=1) mx = fmaxf(mx, __shfl_xor(mx,o));
      float e0=__expf(v0-mx), e1=__expf(v1-mx), e2=__expf(v2-mx), e3=__expf(v3-mx);
      float se = e0+e1+e2+e3;
      float sq = e0*qreg[0][r]+e1*qreg[1][r]+e2*qreg[2][r]+e3*qreg[3][r];
      #pragma unroll
      for (int o=1;o<16;o<<=1){ se += __shfl_xor(se,o); sq += __shfl_xor(sq,o); }
      if (lr == 0) salS[lg*4 + r][w] = sq/se;
    }
  }
  __syncthreads();

  // ---- phase F: v0; yinit = sal * v0 ----
  gemm512_pk16(Hs, Pv + (size_t)w*32768, acc, l, lr, lg);
  {
    float bvv[4];
    #pragma unroll
    for (int j=0;j<4;j++) bvv[j] = bv[w*64 + j*16 + lr];
    #pragma unroll
    for (int r=0;r<4;r++){
      int row = lg*4 + r;
      float s = salS[row][w];
      size_t base = (size_t)(b0+row)*HID + w*64 + lr;
      yinit[base +  0] = s*(acc[0][r]+bvv[0]);
      yinit[base + 16] = s*(acc[1][r]+bvv[1]);
      yinit[base + 32] = s*(acc[2][r]+bvv[2]);
      yinit[base + 48] = s*(acc[3][r]+bvv[3]);
    }
  }
}

// ---------------- FUSED kernel (r11 structure): hln + score + softmax.q + MFMA partial-u ---
__global__ __launch_bounds__(512, 4) void k_fused(
    const float* __restrict__ logsig,
    const __hip_bfloat16* __restrict__ Pip,
    const float* __restrict__ bip,
    const float* __restrict__ g_in, const float* __restrict__ b_in,
    const __hip_bfloat16* __restrict__ Pk,
    const float* __restrict__ bk,
    const float* __restrict__ qws,             // (B,512)
    float* __restrict__ up,                    // (B,NH,4,512) f32 partial u
    float* __restrict__ Asp)                   // (B,NH,4) partial alpha-sum
{
  int b = blockIdx.x, tc = blockIdx.y;
  int tid = threadIdx.x;
  int w = tid >> 6, l = tid & 63, lr = l & 15, lg = l >> 4;
  __shared__ __align__(16) char Hs[64*1024];     // 64 rows x 512 bf16, swizzled
  __shared__ float red[64][8][2];
  __shared__ float ms2[64][2];
  __shared__ float als[64][8];
  __shared__ unsigned short als_bt[2][16][64];   // alpha^T bf16 hi/lo (rows 8-15 unused)

  // ---- stage logsig x-tile (64x64 f32 -> bf16) into Hs cols 0..64 ----
  {
    int row = tid >> 3, cc = (tid & 7)*8;
    const float* srow = logsig + ((size_t)b*T_ + tc*64 + row)*CIN + cc;
    float4 a = *(const float4*)(srow);
    float4 c = *(const float4*)(srow+4);
    uint4 p = { pk2(a.x,a.y), pk2(a.z,a.w), pk2(c.x,c.y), pk2(c.z,c.w) };
    *(uint4*)(Hs + HSOFF(row, cc)) = p;
  }
  __syncthreads();

  // ---- phase 1: Hln = LN(x @ Wip^T + bip) ----
  proj_ln(Hs, Pip, bip, g_in, b_in, red, ms2, tid, w, l, lr, lg);

  // ---- phase 2: scores S = Hln @ Wk_h^T (wave w = head w), A from LDS ----
  f32x4 acc[4][4];
  gemm512_pk(Hs, Pk + (size_t)w*32768, acc, l, lr, lg);

  // ---- phase 3: per-row softmax over head cols, dot q, RK4 weight -> als (+bf16 hi/lo T) ----
  {
    float bkv[4], qv[4];
    #pragma unroll
    for (int j=0;j<4;j++){
      bkv[j] = bk[w*64 + j*16 + lr];
      qv[j]  = qws[(size_t)b*HID + w*64 + j*16 + lr];
    }
    #pragma unroll
    for (int i=0;i<4;i++){
      #pragma unroll
      for (int r=0;r<4;r++){
        float v0 = acc[i][0][r]+bkv[0], v1 = acc[i][1][r]+bkv[1];
        float v2 = acc[i][2][r]+bkv[2], v3 = acc[i][3][r]+bkv[3];
        float mx = fmaxf(fmaxf(v0,v1),fmaxf(v2,v3));
        #pragma unroll
        for (int o=1;o<16;o<<=1) mx = fmaxf(mx, __shfl_xor(mx,o));
        float e0=__expf(v0-mx), e1=__expf(v1-mx), e2=__expf(v2-mx), e3=__expf(v3-mx);
        float se = e0+e1+e2+e3;
        float sq = e0*qv[0]+e1*qv[1]+e2*qv[2]+e3*qv[3];
        #pragma unroll
        for (int o=1;o<16;o<<=1){ se += __shfl_xor(se,o); sq += __shfl_xor(sq,o); }
        if (lr == 0){
          int row = i*16 + lg*4 + r;
          int t = tc*64 + row;
          float wt = (t == 0) ? (5.f/6.f) : ((t == T_-1) ? (1.f/6.f) : 1.f);
          float alpha = wt * sq / se;
          als[row][w] = alpha;
          __hip_bfloat16 ah = __float2bfloat16(alpha);
          float rem = alpha - __bfloat162float(ah);
          als_bt[0][w][row] = __bfloat16_as_ushort(ah);
          als_bt[1][w][row] = __bfloat16_as_ushort(__float2bfloat16(rem));
        }
      }
    }
  }
  __syncthreads();

  // ---- phase 4: u = alpha^T @ H via MFMA (M=8 heads, N=64 cols/wave, K=64 rows) ----
  {
    f32x4 uacc[4];
    #pragma unroll
    for (int t=0;t<4;t++) uacc[t] = (f32x4){0.f,0.f,0.f,0.f};
    #pragma unroll
    for (int ks=0; ks<2; ks++){
      bf16x8 afh = *(const bf16x8*)&als_bt[0][lr][ks*32 + lg*8];
      bf16x8 afl = *(const bf16x8*)&als_bt[1][lr][ks*32 + lg*8];
      #pragma unroll
      for (int t=0;t<4;t++){
        int col = w*64 + t*16 + lr;
        int r0 = ks*32 + lg*8;
        uint4 bbu;
        {
          unsigned lo0 = *(const unsigned short*)(Hs + HSOFF(r0,   col));
          unsigned hi0 = *(const unsigned short*)(Hs + HSOFF(r0+1, col));
          unsigned lo1 = *(const unsigned short*)(Hs + HSOFF(r0+2, col));
          unsigned hi1 = *(const unsigned short*)(Hs + HSOFF(r0+3, col));
          unsigned lo2 = *(const unsigned short*)(Hs + HSOFF(r0+4, col));
          unsigned hi2 = *(const unsigned short*)(Hs + HSOFF(r0+5, col));
          unsigned lo3 = *(const unsigned short*)(Hs + HSOFF(r0+6, col));
          unsigned hi3 = *(const unsigned short*)(Hs + HSOFF(r0+7, col));
          bbu.x = lo0 | (hi0 << 16);
          bbu.y = lo1 | (hi1 << 16);
          bbu.z = lo2 | (hi2 << 16);
          bbu.w = lo3 | (hi3 << 16);
        }
        bf16x8 bvv = __builtin_bit_cast(bf16x8, bbu);
        uacc[t] = __builtin_amdgcn_mfma_f32_16x16x32_bf16(afh, bvv, uacc[t], 0,0,0);
        uacc[t] = __builtin_amdgcn_mfma_f32_16x16x32_bf16(afl, bvv, uacc[t], 0,0,0);
      }
    }
    if (lg < 2){
      #pragma unroll
      for (int t=0;t<4;t++){
        #pragma unroll
        for (int rr=0; rr<4; rr++){
          int h = lg*4 + rr;
          up[((((size_t)b*NH + h)*4 + tc)*HID) + w*64 + t*16 + lr] = uacc[t][rr];
        }
      }
    }
    float s = als[l][w];
    #pragma unroll
    for (int o=1;o<64;o<<=1) s += __shfl_xor(s,o);
    if (l == 0) Asp[(((size_t)b*NH + w)*4) + tc] = s;
  }
}

// ---------------- reduce partials: u_bf (bf16) and Asum ----------------
__global__ __launch_bounds__(256) void k_ured(
    const float* __restrict__ up, const float* __restrict__ Asp,
    __hip_bfloat16* __restrict__ u_bf, float* __restrict__ Asum)
{
  int bh = blockIdx.x, tid = threadIdx.x;
  size_t base = (size_t)bh*4*HID;
  float s0 = 0.f, s1 = 0.f;
  #pragma unroll
  for (int c=0;c<4;c++){
    s0 += up[base + (size_t)c*HID + 2*tid];
    s1 += up[base + (size_t)c*HID + 2*tid+1];
  }
  ((unsigned*)u_bf)[(size_t)bh*(HID/2) + tid] = pk2(s0, s1);
  if (tid == 0)
    Asum[bh] = Asp[(size_t)bh*4] + Asp[(size_t)bh*4+1] + Asp[(size_t)bh*4+2] + Asp[(size_t)bh*4+3];
}

// ---------------- k_tail_a: yh + Wo + LN (dup x4) + quarter FF1 + partial FF2 --------------
// Grid (16, 4): blockIdx.x = 16-row group, blockIdx.y = FF quarter qd.
__global__ __launch_bounds__(512) void k_tail_a(
    const __hip_bfloat16* __restrict__ u_bf,   // (B,8,512)
    const __hip_bfloat16* __restrict__ Pv,
    const float* __restrict__ bv, const float* __restrict__ Asum,
    const float* __restrict__ yinit,
    const __hip_bfloat16* __restrict__ Po, const float* __restrict__ bo,
    const float* __restrict__ g_ff, const float* __restrict__ b_ff,
    const __hip_bfloat16* __restrict__ P1, const float* __restrict__ b1,
    const __hip_bfloat16* __restrict__ P2,
    float* __restrict__ yo,                    // (B,512) f32 (written by qd==0)
    float* __restrict__ yp2)                   // (16,4,16,512) f32 partial y2
{
  int b0 = blockIdx.x*16;
  int qd = blockIdx.y;
  int tid = threadIdx.x;
  int w = tid >> 6, l = tid & 63, lr = l & 15, lg = l >> 4;
  __shared__ __align__(16) char Hs[16*1024];     // 16x512 bf16 swizzled (yh, then yln)
  __shared__ __align__(16) char A1q[16*1024];    // 16x512 bf16 swizzled (ff1 quarter)
  __shared__ float red[16][8][2];
  __shared__ float ms2[16][2];
  f32x4 acc[4];

  // ---- phase 1: yh = u @ Wv_h^T + yinit + bv*Asum -> Hs ----
  #pragma unroll
  for (int j=0;j<4;j++) acc[j] = (f32x4){0.f,0.f,0.f,0.f};
  #pragma unroll
  for (int s = 0; s < 16; s++){
    bf16x8 af = *(const bf16x8*)(u_bf + ((size_t)(b0 + lr)*NH + w)*HID + s*32 + lg*8);
    const __hip_bfloat16* fb = Pv + (size_t)w*32768 + (size_t)s*2048 + l*8;
    #pragma unroll
    for (int j=0;j<4;j++){
      bf16x8 bfr = *(const bf16x8*)(fb + j*512);
      acc[j] = __builtin_amdgcn_mfma_f32_16x16x32_bf16(af, bfr, acc[j], 0,0,0);
    }
  }
  {
    float bvv[4];
    #pragma unroll
    for (int j=0;j<4;j++) bvv[j] = bv[w*64 + j*16 + lr];
    #pragma unroll
    for (int r=0;r<4;r++){
      int row = lg*4 + r;
      float As = Asum[(size_t)(b0+row)*NH + w];
      #pragma unroll
      for (int j=0;j<4;j++){
        int col = w*64 + j*16 + lr;
        float v = acc[j][r] + yinit[(size_t)(b0+row)*HID + col] + bvv[j]*As;
        *(unsigned short*)(Hs + HSOFF(row, col)) =
            __bfloat16_as_ushort(__float2bfloat16(v));
      }
    }
  }
  __syncthreads();

  // ---- phase 2: yo = yh @ Wo^T + bo (regs); LN -> yln overwrites Hs; qd==0 writes yo ----
  gemm512_pk16(Hs, Po + (size_t)w*32768, acc, l, lr, lg);
  {
    float bov[4], gv[4], bbv[4];
    #pragma unroll
    for (int j=0;j<4;j++){
      int col = w*64 + j*16 + lr;
      bov[j] = bo[col]; gv[j] = g_ff[col]; bbv[j] = b_ff[col];
    }
    #pragma unroll
    for (int r=0;r<4;r++){
      int row = lg*4 + r;
      float s = 0.f, s2 = 0.f;
      #pragma unroll
      for (int j=0;j<4;j++){
        float v = acc[j][r] + bov[j];
        s += v; s2 += v*v;
      }
      #pragma unroll
      for (int o=1;o<16;o<<=1){ s += __shfl_xor(s,o); s2 += __shfl_xor(s2,o); }
      if (lr == 0){ red[row][w][0] = s; red[row][w][1] = s2; }
    }
    __syncthreads();
    if (tid < 16){
      float S = 0.f, S2 = 0.f;
      #pragma unroll
      for (int k=0;k<8;k++){ S += red[tid][k][0]; S2 += red[tid][k][1]; }
      float m = S*(1.f/512.f), var = S2*(1.f/512.f) - m*m;
      ms2[tid][0] = m; ms2[tid][1] = rsqrtf(var + 1e-5f);
    }
    __syncthreads();
    #pragma unroll
    for (int r=0;r<4;r++){
      int row = lg*4 + r;
      float m = ms2[row][0], rs = ms2[row][1];
      #pragma unroll
      for (int j=0;j<4;j++){
        int col = w*64 + j*16 + lr;
        float v = acc[j][r] + bov[j];
        if (qd == 0) yo[(size_t)(b0+row)*HID + col] = v;
        *(unsigned short*)(Hs + HSOFF(row, col)) =
            __bfloat16_as_ushort(__float2bfloat16((v - m)*rs*gv[j] + bbv[j]));
      }
    }
  }
  __syncthreads();

  // ---- phase 3': a1 quarter qd: wave w -> W1 tile (qd*8+w); cols local w*64.. ----
  gemm512_pk16(Hs, P1 + (size_t)(qd*8 + w)*32768, acc, l, lr, lg);
  {
    #pragma unroll
    for (int j=0;j<4;j++){
      int lcol = w*64 + j*16 + lr;
      float bc = b1[(qd*8 + w)*64 + j*16 + lr];
      #pragma unroll
      for (int r=0;r<4;r++){
        int row = lg*4 + r;
        *(unsigned short*)(A1q + HSOFF(row, lcol)) =
            __bfloat16_as_ushort(__float2bfloat16(fmaxf(acc[j][r] + bc, 0.f)));
      }
    }
  }
  __syncthreads();

  // ---- phase 4': partial y2 = a1q @ W2[:, qd-quarter]^T -> yp2 ----
  {
    const __hip_bfloat16* Pm = P2 + ((size_t)(w*64 + qd*16)*4)*512;
    gemm512_pk16(A1q, Pm, acc, l, lr, lg);
    #pragma unroll
    for (int r=0;r<4;r++){
      int row = lg*4 + r;
      #pragma unroll
      for (int j=0;j<4;j++){
        int col = w*64 + j*16 + lr;
        yp2[((((size_t)blockIdx.x*4 + qd)*16) + row)*HID + col] = acc[j][r];
      }
    }
  }
}

// ---------------- k_fin: y2 = yo + b2 + sum(partials); out = y2 @ Wf^T + bf ----------------
__global__ __launch_bounds__(512) void k_fin(
    const float* __restrict__ yo, const float* __restrict__ yp2,
    const float* __restrict__ b2,
    const float* __restrict__ Wf, const float* __restrict__ bfv,
    float* __restrict__ out)
{
  int g = blockIdx.x, b0 = g*16;
  int tid = threadIdx.x;
  __shared__ float yoS[16][516];
  for (int i = tid; i < 16*HID; i += 512){
    int row = i >> 9, col = i & 511;
    size_t pb = (((size_t)g*4)*16 + row)*HID + col;
    float v = yo[(size_t)(b0+row)*HID + col] + b2[col]
            + yp2[pb] + yp2[pb + 16*HID] + yp2[pb + 2*16*HID] + yp2[pb + 3*16*HID];
    yoS[row][col] = v;
  }
  __syncthreads();
  {
    int pair = tid >> 1, half = tid & 1;
    if (pair < 16*OUTD){
      int row = pair / OUTD, oc = pair % OUTD;
      const float4* wr = (const float4*)(Wf + (size_t)oc*HID) + half*64;
      float sacc = 0.f;
      #pragma unroll 8
      for (int k4 = 0; k4 < 64; k4++){
        float4 a = wr[k4];
        int c = half*256 + k4*4;
        sacc += a.x*yoS[row][c] + a.y*yoS[row][c+1]
              + a.z*yoS[row][c+2] + a.w*yoS[row][c+3];
      }
      sacc += __shfl_xor(sacc, 1);
      if (half == 0) out[(size_t)(b0+row)*OUTD + oc] = bfv[oc] + sacc;
    }
  }
}

extern "C" void kernel_launch(void* const* d_in, const int* in_sizes, int n_in,
                              void* d_out, int out_size, void* d_ws, size_t ws_size,
                              hipStream_t stream)
{
  const float* initial = (const float*)d_in[0];
  const float* logsig  = (const float*)d_in[1];
  const float* Wi  = (const float*)d_in[2];  const float* bi  = (const float*)d_in[3];
  const float* Wip = (const float*)d_in[4];  const float* bip = (const float*)d_in[5];
  const float* g_in= (const float*)d_in[6];  const float* b_in= (const float*)d_in[7];
  const float* Wk  = (const float*)d_in[8];  const float* bk  = (const float*)d_in[9];
  const float* Wv  = (const float*)d_in[10]; const float* bv  = (const float*)d_in[11];
  const float* Wq  = (const float*)d_in[12]; const float* bq  = (const float*)d_in[13];
  const float* Wo  = (const float*)d_in[14]; const float* bo  = (const float*)d_in[15];
  const float* g_ff= (const float*)d_in[16]; const float* b_ff= (const float*)d_in[17];
  const float* W1  = (const float*)d_in[18]; const float* b1  = (const float*)d_in[19];
  const float* W2  = (const float*)d_in[20]; const float* b2  = (const float*)d_in[21];
  const float* Wf  = (const float*)d_in[22]; const float* bf  = (const float*)d_in[23];
  float* out = (float*)d_out;

  char* ws = (char*)d_ws;
  const size_t MB = 1<<20;
  float* qws   = (float*)(ws);                             // 512 KB
  float* yinit = (float*)(ws + 512*1024);                  // 512 KB
  __hip_bfloat16* u_bf = (__hip_bfloat16*)(ws + 3*MB);     // 2 MB
  float* Asum  = (float*)(ws + 5*MB);                      // 8 KB
  __hip_bfloat16* Pk  = (__hip_bfloat16*)(ws + 5*MB + 512*1024);  // 512 KB
  __hip_bfloat16* Pv  = (__hip_bfloat16*)(ws + 6*MB);      // 512 KB
  __hip_bfloat16* P1  = (__hip_bfloat16*)(ws + 6*MB + 512*1024);  // 2 MB
  __hip_bfloat16* P2  = (__hip_bfloat16*)(ws + 8*MB + 512*1024);  // 2 MB
  float* yo    = (float*)(ws + 10*MB + 512*1024);          // 512 KB
  __hip_bfloat16* Po  = (__hip_bfloat16*)(ws + 13*MB);     // 512 KB
  __hip_bfloat16* Pip = (__hip_bfloat16*)(ws + 15*MB);     // 64 KB
  float* up    = (float*)(ws + 16*MB);                     // 16 MB
  float* Asp   = (float*)(ws + 33*MB);                     // 32 KB
  __hip_bfloat16* Pq  = (__hip_bfloat16*)(ws + 34*MB);     // 512 KB
  __hip_bfloat16* Pi  = (__hip_bfloat16*)(ws + 35*MB);     // 16 KB
  float* yp2   = (float*)(ws + 36*MB);                     // 2 MB

  k_pack<<<dim3((PK_TOT + 255)/256), 256, 0, stream>>>(
      Wk, Wv, Wo, Wq, W1, W2, Wip, Wi,
      Pk, Pv, Po, Pq, P1, P2, Pip, Pi);
  k_pre<<<dim3(B_/16), 512, 0, stream>>>(initial, logsig, Pi, bi, Pip, bip,
                                         g_in, b_in, Pq, bq, Pk, bk, Pv, bv,
                                         qws, yinit);
  k_fused<<<dim3(B_, 4), 512, 0, stream>>>(logsig, Pip, bip, g_in, b_in,
                                           Pk, bk, qws, up, Asp);
  k_ured<<<dim3(B_*NH), 256, 0, stream>>>(up, Asp, u_bf, Asum);
  k_tail_a<<<dim3(B_/16, 4), 512, 0, stream>>>(u_bf, Pv, bv, Asum, yinit,
                                               Po, bo, g_ff, b_ff,
                                               P1, b1, P2, yo, yp2);
  k_fin<<<dim3(B_/16), 512, 0, stream>>>(yo, yp2, b2, Wf, bf, out);
}